// Round 6
// baseline (712.415 us; speedup 1.0000x reference)
//
#include <hip/hip_runtime.h>
#include <math.h>

#define BN_EPS 1e-5f

typedef float floatx4 __attribute__((ext_vector_type(4)));
typedef short shortx4 __attribute__((ext_vector_type(4)));
typedef short shortx8 __attribute__((ext_vector_type(8)));
typedef __bf16 bf16x8 __attribute__((ext_vector_type(8)));

// ---- bf16 helpers (RNE, branch-free; no NaNs in this workload) ----
__device__ __forceinline__ unsigned short f2b(float f) {
    unsigned int u = __builtin_bit_cast(unsigned int, f);
    u += 0x7fffu + ((u >> 16) & 1u);
    return (unsigned short)(u >> 16);
}
__device__ __forceinline__ float b2f(unsigned short s) {
    unsigned int u = ((unsigned int)s) << 16;
    return __builtin_bit_cast(float, u);
}
__device__ __forceinline__ float b2f_s(short s) { return b2f((unsigned short)s); }

// ---------- edge-index layout detection (int32 vs int64 storage) ----------
__global__ __launch_bounds__(256)
void k_detect(const unsigned int* __restrict__ ei, int n_check, int* __restrict__ flag) {
    __shared__ int any;
    if (threadIdx.x == 0) any = 0;
    __syncthreads();
    for (int i = threadIdx.x; i < n_check; i += 256) {
        if (ei[2 * i + 1] != 0u) any = 1;
    }
    __syncthreads();
    if (threadIdx.x == 0) *flag = any;   // 1 => int32 layout, 0 => int64 layout
}

// ---------- degree count straight off the raw edge index ----------
__global__ __launch_bounds__(256)
void k_count(const void* __restrict__ ei_raw, const int* __restrict__ flag,
             int* __restrict__ cnt, int E) {
    int e = blockIdx.x * 256 + threadIdx.x;
    if (e >= E) return;
    int d = (*flag) ? ((const int*)ei_raw)[E + e]
                    : (int)((const long long*)ei_raw)[E + e];
    atomicAdd(&cnt[d], 1);
}

// ---------- 3-phase parallel exclusive scan ----------
__global__ __launch_bounds__(1024)
void k_scan_sum(const int* __restrict__ cnt, int* __restrict__ bsum, int N) {
    __shared__ int s[1024];
    int i = blockIdx.x * 1024 + threadIdx.x;
    s[threadIdx.x] = (i < N) ? cnt[i] : 0;
    __syncthreads();
    for (int off = 512; off > 0; off >>= 1) {
        if (threadIdx.x < off) s[threadIdx.x] += s[threadIdx.x + off];
        __syncthreads();
    }
    if (threadIdx.x == 0) bsum[blockIdx.x] = s[0];
}

__global__ __launch_bounds__(1024)
void k_scan_part(int* __restrict__ bsum, int nb) {
    __shared__ int s[1024];
    int t = threadIdx.x;
    int v = (t < nb) ? bsum[t] : 0;
    s[t] = v;
    __syncthreads();
    for (int off = 1; off < 1024; off <<= 1) {
        int tmp = (t >= off) ? s[t - off] : 0;
        __syncthreads();
        s[t] += tmp;
        __syncthreads();
    }
    if (t < nb) bsum[t] = s[t] - v;     // exclusive
}

__global__ __launch_bounds__(1024)
void k_scan_final(const int* __restrict__ cnt, const int* __restrict__ bsum,
                  int* __restrict__ row_ptr, int* __restrict__ cursor,
                  float* __restrict__ dinv, int N) {
    __shared__ int s[1024];
    int b = blockIdx.x, t = threadIdx.x;
    int i = b * 1024 + t;
    int v = (i < N) ? cnt[i] : 0;
    s[t] = v;
    __syncthreads();
    for (int off = 1; off < 1024; off <<= 1) {
        int tmp = (t >= off) ? s[t - off] : 0;
        __syncthreads();
        s[t] += tmp;
        __syncthreads();
    }
    if (i < N) {
        int excl = bsum[b] + s[t] - v;
        row_ptr[i] = excl;
        cursor[i]  = excl;
        dinv[i] = rsqrtf((float)(v + 1));
        if (i == N - 1) row_ptr[N] = excl + v;
    }
}

// ---------- CSR fill: packed (src, weight) pairs, decoding ei_raw directly ----------
__global__ __launch_bounds__(256)
void k_fill(const void* __restrict__ ei_raw, const int* __restrict__ flag,
            int* __restrict__ cursor, const float* __restrict__ dinv,
            int2* __restrict__ csr_sw, int E) {
    int e = blockIdx.x * 256 + threadIdx.x;
    if (e >= E) return;
    int s, d;
    if (*flag) {
        const int* a = (const int*)ei_raw;
        s = a[e]; d = a[E + e];
    } else {
        const long long* a = (const long long*)ei_raw;
        s = (int)a[e]; d = (int)a[E + e];
    }
    int p = atomicAdd(&cursor[d], 1);
    float w = dinv[s] * dinv[d];
    csr_sw[p] = make_int2(s, __builtin_bit_cast(int, w));
}

// ---------- fused BN1 stats + raw bf16 cast of x (x read ONCE) ----------
__global__ __launch_bounds__(256)
void k_bnstats_cast(const float* __restrict__ x, unsigned short* __restrict__ xb,
                    float* __restrict__ sum8, float* __restrict__ sumsq8, int N, int F) {
    __shared__ float ls[512], lq[512];
    int q   = F >> 2;            // 128 column quads
    int t   = threadIdx.x;
    int cq  = t % q;
    int ro  = t / q;
    int rpp = 256 / q;           // 2
    int step = gridDim.x * rpp;
    float s0 = 0.f, s1 = 0.f, s2 = 0.f, s3 = 0.f;
    float q0 = 0.f, q1 = 0.f, q2 = 0.f, q3 = 0.f;
    size_t colb = (size_t)cq * 4;
    for (int r = blockIdx.x * rpp + ro; r < N; r += 4 * step) {
        int rb = r + step, rc = r + 2 * step, rd = r + 3 * step;
        bool ob = rb < N, oc = rc < N, od = rd < N;
        float4 va = *(const float4*)&x[(size_t)r * F + colb];
        float4 vb, vc, vd;
        if (ob) vb = *(const float4*)&x[(size_t)rb * F + colb];
        if (oc) vc = *(const float4*)&x[(size_t)rc * F + colb];
        if (od) vd = *(const float4*)&x[(size_t)rd * F + colb];
        shortx4 o;
        o[0] = (short)f2b(va.x); o[1] = (short)f2b(va.y);
        o[2] = (short)f2b(va.z); o[3] = (short)f2b(va.w);
        *(shortx4*)&xb[(size_t)r * F + colb] = o;
        s0 += va.x; s1 += va.y; s2 += va.z; s3 += va.w;
        q0 += va.x * va.x; q1 += va.y * va.y; q2 += va.z * va.z; q3 += va.w * va.w;
        if (ob) {
            o[0] = (short)f2b(vb.x); o[1] = (short)f2b(vb.y);
            o[2] = (short)f2b(vb.z); o[3] = (short)f2b(vb.w);
            *(shortx4*)&xb[(size_t)rb * F + colb] = o;
            s0 += vb.x; s1 += vb.y; s2 += vb.z; s3 += vb.w;
            q0 += vb.x * vb.x; q1 += vb.y * vb.y; q2 += vb.z * vb.z; q3 += vb.w * vb.w;
        }
        if (oc) {
            o[0] = (short)f2b(vc.x); o[1] = (short)f2b(vc.y);
            o[2] = (short)f2b(vc.z); o[3] = (short)f2b(vc.w);
            *(shortx4*)&xb[(size_t)rc * F + colb] = o;
            s0 += vc.x; s1 += vc.y; s2 += vc.z; s3 += vc.w;
            q0 += vc.x * vc.x; q1 += vc.y * vc.y; q2 += vc.z * vc.z; q3 += vc.w * vc.w;
        }
        if (od) {
            o[0] = (short)f2b(vd.x); o[1] = (short)f2b(vd.y);
            o[2] = (short)f2b(vd.z); o[3] = (short)f2b(vd.w);
            *(shortx4*)&xb[(size_t)rd * F + colb] = o;
            s0 += vd.x; s1 += vd.y; s2 += vd.z; s3 += vd.w;
            q0 += vd.x * vd.x; q1 += vd.y * vd.y; q2 += vd.z * vd.z; q3 += vd.w * vd.w;
        }
    }
    for (int c = t; c < F; c += 256) { ls[c] = 0.f; lq[c] = 0.f; }
    __syncthreads();
    atomicAdd(&ls[cq * 4 + 0], s0); atomicAdd(&ls[cq * 4 + 1], s1);
    atomicAdd(&ls[cq * 4 + 2], s2); atomicAdd(&ls[cq * 4 + 3], s3);
    atomicAdd(&lq[cq * 4 + 0], q0); atomicAdd(&lq[cq * 4 + 1], q1);
    atomicAdd(&lq[cq * 4 + 2], q2); atomicAdd(&lq[cq * 4 + 3], q3);
    __syncthreads();
    int rep = (blockIdx.x & 7) * F;
    for (int c = t; c < F; c += 256) {
        atomicAdd(&sum8[rep + c],   ls[c]);
        atomicAdd(&sumsq8[rep + c], lq[c]);
    }
}

// ---------- batchnorm column stats on bf16 input (H=256), 4 replicas ----------
__global__ __launch_bounds__(256)
void k_bnstats_b(const unsigned short* __restrict__ x, float* __restrict__ sum,
                 float* __restrict__ sumsq, int N, int H) {
    __shared__ float ls[256], lq[256];
    int t  = threadIdx.x;
    int cg = t & 31;
    int ro = t >> 5;
    int step = gridDim.x * 8;
    float s[8], q[8];
    #pragma unroll
    for (int j = 0; j < 8; ++j) { s[j] = 0.f; q[j] = 0.f; }
    for (int r = blockIdx.x * 8 + ro; r < N; r += step) {
        shortx8 v = *(const shortx8*)&x[(size_t)r * H + cg * 8];
        #pragma unroll
        for (int j = 0; j < 8; ++j) {
            float f = b2f_s(v[j]);
            s[j] += f; q[j] += f * f;
        }
    }
    ls[t] = 0.f; lq[t] = 0.f;
    __syncthreads();
    #pragma unroll
    for (int j = 0; j < 8; ++j) {
        atomicAdd(&ls[cg * 8 + j], s[j]);
        atomicAdd(&lq[cg * 8 + j], q[j]);
    }
    __syncthreads();
    int rep = (blockIdx.x & 3) * H;
    atomicAdd(&sum[rep + t],   ls[t]);
    atomicAdd(&sumsq[rep + t], lq[t]);
}

// ---------- finalize BN affine from nrep replicated partials ----------
__global__ __launch_bounds__(256)
void k_bnfin(const float* __restrict__ sum, const float* __restrict__ sumsq,
             const float* __restrict__ gamma, const float* __restrict__ beta,
             float* __restrict__ a, float* __restrict__ b, int N, int F, int nrep) {
    int c = blockIdx.x * 256 + threadIdx.x;
    if (c >= F) return;
    float s = 0.f, ss = 0.f;
    for (int i = 0; i < nrep; ++i) { s += sum[i * F + c]; ss += sumsq[i * F + c]; }
    float m   = s / (float)N;
    float var = ss / (float)N - m * m;
    float rs  = rsqrtf(var + BN_EPS);
    float aa  = gamma[c] * rs;
    a[c] = aa;
    b[c] = beta[c] - m * aa;
}

// ---------- weight prep: cast+transpose all 4 W (W1 scaled by bna) + cvec tail-blocks ----------
__global__ __launch_bounds__(256)
void k_prep_w(const float* __restrict__ W1, const float* __restrict__ W2,
              const float* __restrict__ W3, const float* __restrict__ W4,
              unsigned short* __restrict__ T1, unsigned short* __restrict__ T2,
              unsigned short* __restrict__ T3, unsigned short* __restrict__ T4,
              const float* __restrict__ bna, const float* __restrict__ bnb,
              float* __restrict__ cvec, int F, int H, int wblocks) {
    if ((int)blockIdx.x >= wblocks) {
        // cvec: c_j = sum_k bnb[k] * W1[k,j]
        int bi = blockIdx.x - wblocks;       // 0..7
        int j = threadIdx.x;                 // H == 256
        int kslice = F / 8;
        int k0 = bi * kslice;
        float s = 0.f;
        for (int k = k0; k < k0 + kslice; ++k)
            s += bnb[k] * W1[(size_t)k * H + j];
        atomicAdd(&cvec[j], s);
        return;
    }
    int i = blockIdx.x * 256 + threadIdx.x;
    int n1 = F * H, n2 = H * H;
    if (i < n1) {
        int n = i / F, k = i % F;
        T1[i] = f2b(W1[(size_t)k * H + n] * bna[k]);
        return;
    }
    const float* W; unsigned short* T; int j;
    if (i < n1 + n2)          { W = W2; T = T2; j = i - n1; }
    else if (i < n1 + 2 * n2) { W = W3; T = T3; j = i - n1 - n2; }
    else if (i < n1 + 3 * n2) { W = W4; T = T4; j = i - n1 - 2 * n2; }
    else return;
    int n = j / H, k = j % H;
    T[j] = f2b(W[(size_t)k * H + n]);
}

// ---------- bf16 MFMA GEMM: C[M,NC] = A[M,K] @ Wt[NC,K]^T ----------
// Operand-swapped mfma -> C^T fragment layout: lane owns row = lane&15,
// 4 consecutive cols per reg quad -> 8B packed stores.
__device__ __forceinline__ void glds16(const void* g, void* l) {
    __builtin_amdgcn_global_load_lds(
        (const __attribute__((address_space(1))) unsigned int*)g,
        (__attribute__((address_space(3))) unsigned int*)l, 16, 0, 0);
}

__global__ __launch_bounds__(256)
void k_gemm_bf16(const unsigned short* __restrict__ A, const unsigned short* __restrict__ Bt,
                 unsigned short* __restrict__ C, int K, int NC) {
    __shared__ unsigned short As[128 * 32];
    __shared__ unsigned short Bs[128 * 32];
    int tid  = threadIdx.x;
    int wave = tid >> 6, lane = tid & 63;
    int row0 = blockIdx.x * 128;
    int col0 = blockIdx.y * 128;
    int wr = (wave & 1) * 64;
    int wc = (wave >> 1) * 64;

    floatx4 acc[4][4];
    #pragma unroll
    for (int i = 0; i < 4; i++)
        #pragma unroll
        for (int j = 0; j < 4; j++) acc[i][j] = (floatx4){0.f, 0.f, 0.f, 0.f};

    int cA = tid * 16;
    int cB = cA + 4096;
    const char* Ab = (const char*)A;
    const char* Bb = (const char*)Bt;
    size_t a_off0 = (size_t)(row0 + (cA >> 6)) * K * 2 + (cA & 63);
    size_t a_off1 = (size_t)(row0 + (cB >> 6)) * K * 2 + (cB & 63);
    size_t b_off0 = (size_t)(col0 + (cA >> 6)) * K * 2 + (cA & 63);
    size_t b_off1 = (size_t)(col0 + (cB >> 6)) * K * 2 + (cB & 63);

    int lm  = lane & 15;
    int lk8 = (lane >> 4) * 8;

    for (int ks = 0; ks < K; ks += 32) {
        size_t koff = (size_t)ks * 2;
        glds16(Ab + a_off0 + koff, (char*)As + cA);
        glds16(Ab + a_off1 + koff, (char*)As + cA + 4096);
        glds16(Bb + b_off0 + koff, (char*)Bs + cA);
        glds16(Bb + b_off1 + koff, (char*)Bs + cA + 4096);
        __syncthreads();

        bf16x8 af[4], bfr[4];
        #pragma unroll
        for (int i = 0; i < 4; i++) {
            shortx8 s = *(const shortx8*)&As[(wr + i * 16 + lm) * 32 + lk8];
            af[i] = __builtin_bit_cast(bf16x8, s);
        }
        #pragma unroll
        for (int j = 0; j < 4; j++) {
            shortx8 s = *(const shortx8*)&Bs[(wc + j * 16 + lm) * 32 + lk8];
            bfr[j] = __builtin_bit_cast(bf16x8, s);
        }
        // swapped operands: acc[i][j] holds C^T fragment
        #pragma unroll
        for (int i = 0; i < 4; i++)
            #pragma unroll
            for (int j = 0; j < 4; j++)
                acc[i][j] = __builtin_amdgcn_mfma_f32_16x16x32_bf16(bfr[j], af[i], acc[i][j], 0, 0, 0);
        __syncthreads();
    }

    // C^T layout: C-row = wr + i*16 + (lane&15); C-col = wc + j*16 + quad*4 + reg
    int quad = lane >> 4;
    int crow0 = row0 + wr + lm;
    int ccol0 = col0 + wc + quad * 4;
    #pragma unroll
    for (int i = 0; i < 4; i++) {
        size_t rbase = (size_t)(crow0 + i * 16) * NC;
        #pragma unroll
        for (int j = 0; j < 4; j++) {
            shortx4 o;
            o[0] = (short)f2b(acc[i][j][0]);
            o[1] = (short)f2b(acc[i][j][1]);
            o[2] = (short)f2b(acc[i][j][2]);
            o[3] = (short)f2b(acc[i][j][3]);
            *(shortx4*)&C[rbase + ccol0 + j * 16] = o;
        }
    }
}

// ---------- CSR gather-aggregation: wave per node, half-wave per edge slot ----------
// 16-edge main loop (8 rows in flight/lane), 8-edge mid, predicated 8-slot tail.
__global__ __launch_bounds__(256)
void k_agg(const unsigned short* __restrict__ hin, unsigned short* __restrict__ hout,
           const int* __restrict__ row_ptr, const int2* __restrict__ csr_sw,
           const float* __restrict__ dinv, const float* __restrict__ bias,
           const float* __restrict__ cvec, int N) {
    const int H = 256;
    int node = blockIdx.x * 4 + (threadIdx.x >> 6);
    if (node >= N) return;
    int lane = threadIdx.x & 63;
    int half = lane >> 5;
    int f = (lane & 31) * 8;
    int e0 = row_ptr[node], e1 = row_ptr[node + 1];
    float di = dinv[node];
    float acc[8];
    float ws;
    if (half == 0) {
        shortx8 hv = *(const shortx8*)&hin[(size_t)node * H + f];
        float sl = di * di;
        ws = sl;
        #pragma unroll
        for (int j = 0; j < 8; ++j) acc[j] = b2f_s(hv[j]) * sl;
    } else {
        ws = 0.f;
        #pragma unroll
        for (int j = 0; j < 8; ++j) acc[j] = 0.f;
    }
    int e = e0;
    for (; e + 16 <= e1; e += 16) {
        int2 pp[8];
        #pragma unroll
        for (int k = 0; k < 8; ++k) pp[k] = csr_sw[e + 2 * k + half];
        shortx8 rr[8];
        #pragma unroll
        for (int k = 0; k < 8; ++k)
            rr[k] = *(const shortx8*)&hin[(size_t)pp[k].x * H + f];
        #pragma unroll
        for (int k = 0; k < 8; ++k) {
            float w = __builtin_bit_cast(float, pp[k].y);
            ws += w;
            #pragma unroll
            for (int j = 0; j < 8; ++j) acc[j] += w * b2f_s(rr[k][j]);
        }
    }
    if (e + 8 <= e1) {
        int2 pp[4];
        #pragma unroll
        for (int k = 0; k < 4; ++k) pp[k] = csr_sw[e + 2 * k + half];
        shortx8 rr[4];
        #pragma unroll
        for (int k = 0; k < 4; ++k)
            rr[k] = *(const shortx8*)&hin[(size_t)pp[k].x * H + f];
        #pragma unroll
        for (int k = 0; k < 4; ++k) {
            float w = __builtin_bit_cast(float, pp[k].y);
            ws += w;
            #pragma unroll
            for (int j = 0; j < 8; ++j) acc[j] += w * b2f_s(rr[k][j]);
        }
        e += 8;
    }
    if (e < e1) {
        // predicated tail: up to 7 edges, clamped loads, zero weight on invalid
        int2 pp[4]; float wv[4];
        #pragma unroll
        for (int k = 0; k < 4; ++k) {
            int idx = e + 2 * k + half;
            bool v = idx < e1;
            pp[k] = csr_sw[v ? idx : e];
            wv[k] = v ? __builtin_bit_cast(float, pp[k].y) : 0.f;
        }
        shortx8 rr[4];
        #pragma unroll
        for (int k = 0; k < 4; ++k)
            rr[k] = *(const shortx8*)&hin[(size_t)pp[k].x * H + f];
        #pragma unroll
        for (int k = 0; k < 4; ++k) {
            ws += wv[k];
            #pragma unroll
            for (int j = 0; j < 8; ++j) acc[j] += wv[k] * b2f_s(rr[k][j]);
        }
    }
    #pragma unroll
    for (int j = 0; j < 8; ++j) acc[j] += __shfl_xor(acc[j], 32, 64);
    ws += __shfl_xor(ws, 32, 64);
    if (half == 0) {
        float4 bi0 = *(const float4*)&bias[f];
        float4 bi1 = *(const float4*)&bias[f + 4];
        if (cvec) {
            float4 c0 = *(const float4*)&cvec[f];
            float4 c1 = *(const float4*)&cvec[f + 4];
            bi0.x += ws * c0.x; bi0.y += ws * c0.y;
            bi0.z += ws * c0.z; bi0.w += ws * c0.w;
            bi1.x += ws * c1.x; bi1.y += ws * c1.y;
            bi1.z += ws * c1.z; bi1.w += ws * c1.w;
        }
        shortx8 o;
        o[0] = (short)f2b(acc[0] + bi0.x);
        o[1] = (short)f2b(acc[1] + bi0.y);
        o[2] = (short)f2b(acc[2] + bi0.z);
        o[3] = (short)f2b(acc[3] + bi0.w);
        o[4] = (short)f2b(acc[4] + bi1.x);
        o[5] = (short)f2b(acc[5] + bi1.y);
        o[6] = (short)f2b(acc[6] + bi1.z);
        o[7] = (short)f2b(acc[7] + bi1.w);
        *(shortx8*)&hout[(size_t)node * H + f] = o;
    }
}

// ---------- head: BN2 affine + [256x5] dense + sigmoid, 4 nodes per block ----------
__global__ __launch_bounds__(256)
void k_head(const unsigned short* __restrict__ h, const float* __restrict__ a,
            const float* __restrict__ b, const float* __restrict__ Wd,
            const float* __restrict__ bd, float* __restrict__ out, int N) {
    int node = blockIdx.x * 4 + (threadIdx.x >> 6);
    if (node >= N) return;
    int lane = threadIdx.x & 63;
    int f = lane * 4;
    shortx4 hv = *(const shortx4*)&h[(size_t)node * 256 + f];
    float v0 = b2f_s(hv[0]) * a[f + 0] + b[f + 0];
    float v1 = b2f_s(hv[1]) * a[f + 1] + b[f + 1];
    float v2 = b2f_s(hv[2]) * a[f + 2] + b[f + 2];
    float v3 = b2f_s(hv[3]) * a[f + 3] + b[f + 3];
    float s[5];
    #pragma unroll
    for (int j = 0; j < 5; ++j) {
        s[j] = v0 * Wd[(f + 0) * 5 + j] + v1 * Wd[(f + 1) * 5 + j] +
               v2 * Wd[(f + 2) * 5 + j] + v3 * Wd[(f + 3) * 5 + j];
    }
    #pragma unroll
    for (int off = 32; off > 0; off >>= 1) {
        #pragma unroll
        for (int j = 0; j < 5; ++j) s[j] += __shfl_down(s[j], off, 64);
    }
    if (lane == 0) {
        #pragma unroll
        for (int j = 0; j < 5; ++j) {
            float z = s[j] + bd[j];
            out[(size_t)node * 5 + j] = 1.f / (1.f + expf(-z));
        }
    }
}

extern "C" void kernel_launch(void* const* d_in, const int* in_sizes, int n_in,
                              void* d_out, int out_size, void* d_ws, size_t ws_size,
                              hipStream_t stream) {
    const float* x      = (const float*)d_in[0];
    const void*  ei_raw = d_in[1];
    const float* gamma1 = (const float*)d_in[2];
    const float* beta1  = (const float*)d_in[3];
    const float* W1 = (const float*)d_in[4];
    const float* b1 = (const float*)d_in[5];
    const float* W2 = (const float*)d_in[6];
    const float* b2 = (const float*)d_in[7];
    const float* W3 = (const float*)d_in[8];
    const float* b3 = (const float*)d_in[9];
    const float* W4 = (const float*)d_in[10];
    const float* b4 = (const float*)d_in[11];
    const float* gamma2 = (const float*)d_in[12];
    const float* beta2  = (const float*)d_in[13];
    const float* Wd = (const float*)d_in[14];
    const float* bd = (const float*)d_in[15];

    const int F = in_sizes[2];        // 512
    const int N = in_sizes[0] / F;    // 50000
    const int E = in_sizes[1] / 2;    // 800000
    const int H = in_sizes[5];        // 256
    const int Mpad = ((N + 127) / 128) * 128;   // 50048
    const int NB   = (N + 1023) / 1024;
    float* out = (float*)d_out;

    char* p = (char*)d_ws;
    auto alloc = [&](size_t bytes) {
        void* r = (void*)p;
        p += (bytes + 255) & ~(size_t)255;
        return r;
    };
    int*   flag    = (int*)  alloc(4);
    // ---- contiguous zero-init group ----
    char*  zstart  = p;
    int*   cnt     = (int*)  alloc((size_t)N * 4);
    float* colsum8 = (float*)alloc((size_t)8 * F * 4);
    float* colsq8  = (float*)alloc((size_t)8 * F * 4);
    float* colsum2 = (float*)alloc((size_t)4 * H * 4);
    float* colsq2  = (float*)alloc((size_t)4 * H * 4);
    float* cvec    = (float*)alloc((size_t)H * 4);
    size_t zbytes  = (size_t)(p - zstart);
    int*   row_ptr = (int*)  alloc(((size_t)N + 1) * 4);
    int*   cursor  = (int*)  alloc((size_t)N * 4);
    float* dinv    = (float*)alloc((size_t)N * 4);
    int2*  csr_sw  = (int2*) alloc((size_t)E * 8);
    int*   bsum    = (int*)  alloc((size_t)NB * 4);
    float* bna     = (float*)alloc((size_t)F * 4);
    float* bnb     = (float*)alloc((size_t)F * 4);
    unsigned short* W1t = (unsigned short*)alloc((size_t)F * H * 2);
    unsigned short* W2t = (unsigned short*)alloc((size_t)H * H * 2);
    unsigned short* W3t = (unsigned short*)alloc((size_t)H * H * 2);
    unsigned short* W4t = (unsigned short*)alloc((size_t)H * H * 2);
    unsigned short* xb  = (unsigned short*)alloc((size_t)Mpad * F * 2);
    unsigned short* hbA = (unsigned short*)alloc((size_t)Mpad * H * 2);
    unsigned short* hbB = (unsigned short*)alloc((size_t)Mpad * H * 2);

    hipMemsetAsync(zstart, 0, zbytes, stream);
    hipMemsetAsync(xb + (size_t)N * F, 0, (size_t)(Mpad - N) * F * 2, stream);

    // graph build
    int n_check = (E >= 2048) ? 2048 : E;
    k_detect<<<1, 256, 0, stream>>>((const unsigned int*)ei_raw, n_check, flag);
    k_count<<<(E + 255) / 256, 256, 0, stream>>>(ei_raw, flag, cnt, E);
    k_scan_sum<<<NB, 1024, 0, stream>>>(cnt, bsum, N);
    k_scan_part<<<1, 1024, 0, stream>>>(bsum, NB);
    k_scan_final<<<NB, 1024, 0, stream>>>(cnt, bsum, row_ptr, cursor, dinv, N);
    k_fill<<<(E + 255) / 256, 256, 0, stream>>>(ei_raw, flag, cursor, dinv, csr_sw, E);

    // BN1 stats + raw cast (single pass over x)
    k_bnstats_cast<<<2048, 256, 0, stream>>>(x, xb, colsum8, colsq8, N, F);
    k_bnfin<<<(F + 255) / 256, 256, 0, stream>>>(colsum8, colsq8, gamma1, beta1, bna, bnb, N, F, 8);

    // weight prep (W1 scaled by bna) + cvec in one launch
    int tot = F * H + 3 * H * H;
    int wblocks = (tot + 255) / 256;
    k_prep_w<<<wblocks + 8, 256, 0, stream>>>(W1, W2, W3, W4, W1t, W2t, W3t, W4t,
                                              bna, bnb, cvec, F, H, wblocks);

    dim3 gg(Mpad / 128, H / 128);
    int aggb = (N + 3) / 4;
    // conv1 (BN1 folded: xb raw, W1t pre-scaled, cvec correction via wsum)
    k_gemm_bf16<<<gg, 256, 0, stream>>>(xb, W1t, hbA, F, H);
    k_agg<<<aggb, 256, 0, stream>>>(hbA, hbB, row_ptr, csr_sw, dinv, b1, cvec, N);
    // conv2
    k_gemm_bf16<<<gg, 256, 0, stream>>>(hbB, W2t, hbA, H, H);
    k_agg<<<aggb, 256, 0, stream>>>(hbA, hbB, row_ptr, csr_sw, dinv, b2, nullptr, N);
    // conv3
    k_gemm_bf16<<<gg, 256, 0, stream>>>(hbB, W3t, hbA, H, H);
    k_agg<<<aggb, 256, 0, stream>>>(hbA, hbB, row_ptr, csr_sw, dinv, b3, nullptr, N);
    // conv4
    k_gemm_bf16<<<gg, 256, 0, stream>>>(hbB, W4t, hbA, H, H);
    k_agg<<<aggb, 256, 0, stream>>>(hbA, hbB, row_ptr, csr_sw, dinv, b4, nullptr, N);

    // BN2 + head
    k_bnstats_b<<<1024, 256, 0, stream>>>(hbB, colsum2, colsq2, N, H);
    k_bnfin<<<(H + 255) / 256, 256, 0, stream>>>(colsum2, colsq2, gamma2, beta2, bna, bnb, N, H, 4);
    k_head<<<(N + 3) / 4, 256, 0, stream>>>(hbB, bna, bnb, Wd, bd, out, N);
}

// Round 7
// 709.307 us; speedup vs baseline: 1.0044x; 1.0044x over previous
//
#include <hip/hip_runtime.h>
#include <math.h>

#define BN_EPS 1e-5f

typedef float floatx4 __attribute__((ext_vector_type(4)));
typedef short shortx4 __attribute__((ext_vector_type(4)));
typedef short shortx8 __attribute__((ext_vector_type(8)));
typedef __bf16 bf16x8 __attribute__((ext_vector_type(8)));

// ---- bf16 helpers (RNE, branch-free; no NaNs in this workload) ----
__device__ __forceinline__ unsigned short f2b(float f) {
    unsigned int u = __builtin_bit_cast(unsigned int, f);
    u += 0x7fffu + ((u >> 16) & 1u);
    return (unsigned short)(u >> 16);
}
__device__ __forceinline__ float b2f(unsigned short s) {
    unsigned int u = ((unsigned int)s) << 16;
    return __builtin_bit_cast(float, u);
}
__device__ __forceinline__ float b2f_s(short s) { return b2f((unsigned short)s); }

// ---------- edge-index layout detection (int32 vs int64 storage) ----------
__global__ __launch_bounds__(256)
void k_detect(const unsigned int* __restrict__ ei, int n_check, int* __restrict__ flag) {
    __shared__ int any;
    if (threadIdx.x == 0) any = 0;
    __syncthreads();
    for (int i = threadIdx.x; i < n_check; i += 256) {
        if (ei[2 * i + 1] != 0u) any = 1;
    }
    __syncthreads();
    if (threadIdx.x == 0) *flag = any;   // 1 => int32 layout, 0 => int64 layout
}

// ---------- degree count straight off the raw edge index ----------
__global__ __launch_bounds__(256)
void k_count(const void* __restrict__ ei_raw, const int* __restrict__ flag,
             int* __restrict__ cnt, int E) {
    int e = blockIdx.x * 256 + threadIdx.x;
    if (e >= E) return;
    int d = (*flag) ? ((const int*)ei_raw)[E + e]
                    : (int)((const long long*)ei_raw)[E + e];
    atomicAdd(&cnt[d], 1);
}

// ---------- 3-phase parallel exclusive scan ----------
__global__ __launch_bounds__(1024)
void k_scan_sum(const int* __restrict__ cnt, int* __restrict__ bsum, int N) {
    __shared__ int s[1024];
    int i = blockIdx.x * 1024 + threadIdx.x;
    s[threadIdx.x] = (i < N) ? cnt[i] : 0;
    __syncthreads();
    for (int off = 512; off > 0; off >>= 1) {
        if (threadIdx.x < off) s[threadIdx.x] += s[threadIdx.x + off];
        __syncthreads();
    }
    if (threadIdx.x == 0) bsum[blockIdx.x] = s[0];
}

__global__ __launch_bounds__(1024)
void k_scan_part(int* __restrict__ bsum, int nb) {
    __shared__ int s[1024];
    int t = threadIdx.x;
    int v = (t < nb) ? bsum[t] : 0;
    s[t] = v;
    __syncthreads();
    for (int off = 1; off < 1024; off <<= 1) {
        int tmp = (t >= off) ? s[t - off] : 0;
        __syncthreads();
        s[t] += tmp;
        __syncthreads();
    }
    if (t < nb) bsum[t] = s[t] - v;     // exclusive
}

__global__ __launch_bounds__(1024)
void k_scan_final(const int* __restrict__ cnt, const int* __restrict__ bsum,
                  int* __restrict__ row_ptr, int* __restrict__ cursor,
                  float* __restrict__ dinv, int N) {
    __shared__ int s[1024];
    int b = blockIdx.x, t = threadIdx.x;
    int i = b * 1024 + t;
    int v = (i < N) ? cnt[i] : 0;
    s[t] = v;
    __syncthreads();
    for (int off = 1; off < 1024; off <<= 1) {
        int tmp = (t >= off) ? s[t - off] : 0;
        __syncthreads();
        s[t] += tmp;
        __syncthreads();
    }
    if (i < N) {
        int excl = bsum[b] + s[t] - v;
        row_ptr[i] = excl;
        cursor[i]  = excl;
        dinv[i] = rsqrtf((float)(v + 1));
        if (i == N - 1) row_ptr[N] = excl + v;
    }
}

// ---------- CSR fill: packed (src, weight) pairs, decoding ei_raw directly ----------
__global__ __launch_bounds__(256)
void k_fill(const void* __restrict__ ei_raw, const int* __restrict__ flag,
            int* __restrict__ cursor, const float* __restrict__ dinv,
            int2* __restrict__ csr_sw, int E) {
    int e = blockIdx.x * 256 + threadIdx.x;
    if (e >= E) return;
    int s, d;
    if (*flag) {
        const int* a = (const int*)ei_raw;
        s = a[e]; d = a[E + e];
    } else {
        const long long* a = (const long long*)ei_raw;
        s = (int)a[e]; d = (int)a[E + e];
    }
    int p = atomicAdd(&cursor[d], 1);
    float w = dinv[s] * dinv[d];
    csr_sw[p] = make_int2(s, __builtin_bit_cast(int, w));
}

// ---------- fused BN1 stats + raw bf16 cast of x (x read ONCE) ----------
__global__ __launch_bounds__(256)
void k_bnstats_cast(const float* __restrict__ x, unsigned short* __restrict__ xb,
                    float* __restrict__ sum8, float* __restrict__ sumsq8, int N, int F) {
    __shared__ float ls[512], lq[512];
    int q   = F >> 2;            // 128 column quads
    int t   = threadIdx.x;
    int cq  = t % q;
    int ro  = t / q;
    int rpp = 256 / q;           // 2
    int step = gridDim.x * rpp;
    float s0 = 0.f, s1 = 0.f, s2 = 0.f, s3 = 0.f;
    float q0 = 0.f, q1 = 0.f, q2 = 0.f, q3 = 0.f;
    size_t colb = (size_t)cq * 4;
    for (int r = blockIdx.x * rpp + ro; r < N; r += 4 * step) {
        int rb = r + step, rc = r + 2 * step, rd = r + 3 * step;
        bool ob = rb < N, oc = rc < N, od = rd < N;
        float4 va = *(const float4*)&x[(size_t)r * F + colb];
        float4 vb, vc, vd;
        if (ob) vb = *(const float4*)&x[(size_t)rb * F + colb];
        if (oc) vc = *(const float4*)&x[(size_t)rc * F + colb];
        if (od) vd = *(const float4*)&x[(size_t)rd * F + colb];
        shortx4 o;
        o[0] = (short)f2b(va.x); o[1] = (short)f2b(va.y);
        o[2] = (short)f2b(va.z); o[3] = (short)f2b(va.w);
        *(shortx4*)&xb[(size_t)r * F + colb] = o;
        s0 += va.x; s1 += va.y; s2 += va.z; s3 += va.w;
        q0 += va.x * va.x; q1 += va.y * va.y; q2 += va.z * va.z; q3 += va.w * va.w;
        if (ob) {
            o[0] = (short)f2b(vb.x); o[1] = (short)f2b(vb.y);
            o[2] = (short)f2b(vb.z); o[3] = (short)f2b(vb.w);
            *(shortx4*)&xb[(size_t)rb * F + colb] = o;
            s0 += vb.x; s1 += vb.y; s2 += vb.z; s3 += vb.w;
            q0 += vb.x * vb.x; q1 += vb.y * vb.y; q2 += vb.z * vb.z; q3 += vb.w * vb.w;
        }
        if (oc) {
            o[0] = (short)f2b(vc.x); o[1] = (short)f2b(vc.y);
            o[2] = (short)f2b(vc.z); o[3] = (short)f2b(vc.w);
            *(shortx4*)&xb[(size_t)rc * F + colb] = o;
            s0 += vc.x; s1 += vc.y; s2 += vc.z; s3 += vc.w;
            q0 += vc.x * vc.x; q1 += vc.y * vc.y; q2 += vc.z * vc.z; q3 += vc.w * vc.w;
        }
        if (od) {
            o[0] = (short)f2b(vd.x); o[1] = (short)f2b(vd.y);
            o[2] = (short)f2b(vd.z); o[3] = (short)f2b(vd.w);
            *(shortx4*)&xb[(size_t)rd * F + colb] = o;
            s0 += vd.x; s1 += vd.y; s2 += vd.z; s3 += vd.w;
            q0 += vd.x * vd.x; q1 += vd.y * vd.y; q2 += vd.z * vd.z; q3 += vd.w * vd.w;
        }
    }
    for (int c = t; c < F; c += 256) { ls[c] = 0.f; lq[c] = 0.f; }
    __syncthreads();
    atomicAdd(&ls[cq * 4 + 0], s0); atomicAdd(&ls[cq * 4 + 1], s1);
    atomicAdd(&ls[cq * 4 + 2], s2); atomicAdd(&ls[cq * 4 + 3], s3);
    atomicAdd(&lq[cq * 4 + 0], q0); atomicAdd(&lq[cq * 4 + 1], q1);
    atomicAdd(&lq[cq * 4 + 2], q2); atomicAdd(&lq[cq * 4 + 3], q3);
    __syncthreads();
    int rep = (blockIdx.x & 7) * F;
    for (int c = t; c < F; c += 256) {
        atomicAdd(&sum8[rep + c],   ls[c]);
        atomicAdd(&sumsq8[rep + c], lq[c]);
    }
}

// ---------- batchnorm column stats on bf16 input (H=256), 4 replicas ----------
__global__ __launch_bounds__(256)
void k_bnstats_b(const unsigned short* __restrict__ x, float* __restrict__ sum,
                 float* __restrict__ sumsq, int N, int H) {
    __shared__ float ls[256], lq[256];
    int t  = threadIdx.x;
    int cg = t & 31;
    int ro = t >> 5;
    int step = gridDim.x * 8;
    float s[8], q[8];
    #pragma unroll
    for (int j = 0; j < 8; ++j) { s[j] = 0.f; q[j] = 0.f; }
    for (int r = blockIdx.x * 8 + ro; r < N; r += step) {
        shortx8 v = *(const shortx8*)&x[(size_t)r * H + cg * 8];
        #pragma unroll
        for (int j = 0; j < 8; ++j) {
            float f = b2f_s(v[j]);
            s[j] += f; q[j] += f * f;
        }
    }
    ls[t] = 0.f; lq[t] = 0.f;
    __syncthreads();
    #pragma unroll
    for (int j = 0; j < 8; ++j) {
        atomicAdd(&ls[cg * 8 + j], s[j]);
        atomicAdd(&lq[cg * 8 + j], q[j]);
    }
    __syncthreads();
    int rep = (blockIdx.x & 3) * H;
    atomicAdd(&sum[rep + t],   ls[t]);
    atomicAdd(&sumsq[rep + t], lq[t]);
}

// ---------- finalize BN affine from nrep replicated partials ----------
__global__ __launch_bounds__(256)
void k_bnfin(const float* __restrict__ sum, const float* __restrict__ sumsq,
             const float* __restrict__ gamma, const float* __restrict__ beta,
             float* __restrict__ a, float* __restrict__ b, int N, int F, int nrep) {
    int c = blockIdx.x * 256 + threadIdx.x;
    if (c >= F) return;
    float s = 0.f, ss = 0.f;
    for (int i = 0; i < nrep; ++i) { s += sum[i * F + c]; ss += sumsq[i * F + c]; }
    float m   = s / (float)N;
    float var = ss / (float)N - m * m;
    float rs  = rsqrtf(var + BN_EPS);
    float aa  = gamma[c] * rs;
    a[c] = aa;
    b[c] = beta[c] - m * aa;
}

// ---------- weight prep: cast+transpose all 4 W (W1 scaled by bna) + cvec tail-blocks ----------
__global__ __launch_bounds__(256)
void k_prep_w(const float* __restrict__ W1, const float* __restrict__ W2,
              const float* __restrict__ W3, const float* __restrict__ W4,
              unsigned short* __restrict__ T1, unsigned short* __restrict__ T2,
              unsigned short* __restrict__ T3, unsigned short* __restrict__ T4,
              const float* __restrict__ bna, const float* __restrict__ bnb,
              float* __restrict__ cvec, int F, int H, int wblocks) {
    if ((int)blockIdx.x >= wblocks) {
        // cvec: c_j = sum_k bnb[k] * W1[k,j]
        int bi = blockIdx.x - wblocks;       // 0..7
        int j = threadIdx.x;                 // H == 256
        int kslice = F / 8;
        int k0 = bi * kslice;
        float s = 0.f;
        for (int k = k0; k < k0 + kslice; ++k)
            s += bnb[k] * W1[(size_t)k * H + j];
        atomicAdd(&cvec[j], s);
        return;
    }
    int i = blockIdx.x * 256 + threadIdx.x;
    int n1 = F * H, n2 = H * H;
    if (i < n1) {
        int n = i / F, k = i % F;
        T1[i] = f2b(W1[(size_t)k * H + n] * bna[k]);
        return;
    }
    const float* W; unsigned short* T; int j;
    if (i < n1 + n2)          { W = W2; T = T2; j = i - n1; }
    else if (i < n1 + 2 * n2) { W = W3; T = T3; j = i - n1 - n2; }
    else if (i < n1 + 3 * n2) { W = W4; T = T4; j = i - n1 - 2 * n2; }
    else return;
    int n = j / H, k = j % H;
    T[j] = f2b(W[(size_t)k * H + n]);
}

// ---------- bf16 MFMA GEMM: C[M,NC] = A[M,K] @ Wt[NC,K]^T ----------
// Operand-swapped mfma -> C^T fragment layout -> 8B packed coalesced stores.
__device__ __forceinline__ void glds16(const void* g, void* l) {
    __builtin_amdgcn_global_load_lds(
        (const __attribute__((address_space(1))) unsigned int*)g,
        (__attribute__((address_space(3))) unsigned int*)l, 16, 0, 0);
}

__global__ __launch_bounds__(256)
void k_gemm_bf16(const unsigned short* __restrict__ A, const unsigned short* __restrict__ Bt,
                 unsigned short* __restrict__ C, int K, int NC) {
    __shared__ unsigned short As[128 * 32];
    __shared__ unsigned short Bs[128 * 32];
    int tid  = threadIdx.x;
    int wave = tid >> 6, lane = tid & 63;
    int row0 = blockIdx.x * 128;
    int col0 = blockIdx.y * 128;
    int wr = (wave & 1) * 64;
    int wc = (wave >> 1) * 64;

    floatx4 acc[4][4];
    #pragma unroll
    for (int i = 0; i < 4; i++)
        #pragma unroll
        for (int j = 0; j < 4; j++) acc[i][j] = (floatx4){0.f, 0.f, 0.f, 0.f};

    int cA = tid * 16;
    int cB = cA + 4096;
    const char* Ab = (const char*)A;
    const char* Bb = (const char*)Bt;
    size_t a_off0 = (size_t)(row0 + (cA >> 6)) * K * 2 + (cA & 63);
    size_t a_off1 = (size_t)(row0 + (cB >> 6)) * K * 2 + (cB & 63);
    size_t b_off0 = (size_t)(col0 + (cA >> 6)) * K * 2 + (cA & 63);
    size_t b_off1 = (size_t)(col0 + (cB >> 6)) * K * 2 + (cB & 63);

    int lm  = lane & 15;
    int lk8 = (lane >> 4) * 8;

    for (int ks = 0; ks < K; ks += 32) {
        size_t koff = (size_t)ks * 2;
        glds16(Ab + a_off0 + koff, (char*)As + cA);
        glds16(Ab + a_off1 + koff, (char*)As + cA + 4096);
        glds16(Bb + b_off0 + koff, (char*)Bs + cA);
        glds16(Bb + b_off1 + koff, (char*)Bs + cA + 4096);
        __syncthreads();

        bf16x8 af[4], bfr[4];
        #pragma unroll
        for (int i = 0; i < 4; i++) {
            shortx8 s = *(const shortx8*)&As[(wr + i * 16 + lm) * 32 + lk8];
            af[i] = __builtin_bit_cast(bf16x8, s);
        }
        #pragma unroll
        for (int j = 0; j < 4; j++) {
            shortx8 s = *(const shortx8*)&Bs[(wc + j * 16 + lm) * 32 + lk8];
            bfr[j] = __builtin_bit_cast(bf16x8, s);
        }
        // swapped operands: acc[i][j] holds C^T fragment
        #pragma unroll
        for (int i = 0; i < 4; i++)
            #pragma unroll
            for (int j = 0; j < 4; j++)
                acc[i][j] = __builtin_amdgcn_mfma_f32_16x16x32_bf16(bfr[j], af[i], acc[i][j], 0, 0, 0);
        __syncthreads();
    }

    // C^T layout: C-row = wr + i*16 + (lane&15); C-col = wc + j*16 + quad*4 + reg
    int quad = lane >> 4;
    int crow0 = row0 + wr + lm;
    int ccol0 = col0 + wc + quad * 4;
    #pragma unroll
    for (int i = 0; i < 4; i++) {
        size_t rbase = (size_t)(crow0 + i * 16) * NC;
        #pragma unroll
        for (int j = 0; j < 4; j++) {
            shortx4 o;
            o[0] = (short)f2b(acc[i][j][0]);
            o[1] = (short)f2b(acc[i][j][1]);
            o[2] = (short)f2b(acc[i][j][2]);
            o[3] = (short)f2b(acc[i][j][3]);
            *(shortx4*)&C[rbase + ccol0 + j * 16] = o;
        }
    }
}

// ---------- CSR gather-aggregation (R5 shape: 8-edge main, predicated tail) ----------
// Wave per node, half-wave per edge slot, lane owns 8 features (16B loads).
__global__ __launch_bounds__(256)
void k_agg(const unsigned short* __restrict__ hin, unsigned short* __restrict__ hout,
           const int* __restrict__ row_ptr, const int2* __restrict__ csr_sw,
           const float* __restrict__ dinv, const float* __restrict__ bias, int N) {
    const int H = 256;
    int node = blockIdx.x * 4 + (threadIdx.x >> 6);
    if (node >= N) return;
    int lane = threadIdx.x & 63;
    int half = lane >> 5;
    int f = (lane & 31) * 8;
    float acc[8];
    float di = dinv[node];
    if (half == 0) {
        shortx8 hv = *(const shortx8*)&hin[(size_t)node * H + f];
        float sl = di * di;
        #pragma unroll
        for (int j = 0; j < 8; ++j) acc[j] = b2f_s(hv[j]) * sl;
    } else {
        #pragma unroll
        for (int j = 0; j < 8; ++j) acc[j] = 0.f;
    }
    int e0 = row_ptr[node], e1 = row_ptr[node + 1];
    int e = e0;
    for (; e + 8 <= e1; e += 8) {
        int2 p0 = csr_sw[e + 0 + half];
        int2 p1 = csr_sw[e + 2 + half];
        int2 p2 = csr_sw[e + 4 + half];
        int2 p3 = csr_sw[e + 6 + half];
        shortx8 r0 = *(const shortx8*)&hin[(size_t)p0.x * H + f];
        shortx8 r1 = *(const shortx8*)&hin[(size_t)p1.x * H + f];
        shortx8 r2 = *(const shortx8*)&hin[(size_t)p2.x * H + f];
        shortx8 r3 = *(const shortx8*)&hin[(size_t)p3.x * H + f];
        float w0 = __builtin_bit_cast(float, p0.y);
        float w1 = __builtin_bit_cast(float, p1.y);
        float w2 = __builtin_bit_cast(float, p2.y);
        float w3 = __builtin_bit_cast(float, p3.y);
        #pragma unroll
        for (int j = 0; j < 8; ++j)
            acc[j] += w0 * b2f_s(r0[j]) + w1 * b2f_s(r1[j])
                    + w2 * b2f_s(r2[j]) + w3 * b2f_s(r3[j]);
    }
    for (; e < e1; e += 2) {
        int idx = e + half;
        bool valid = idx < e1;
        int2 pr = csr_sw[valid ? idx : e];
        float w = valid ? __builtin_bit_cast(float, pr.y) : 0.f;
        shortx8 r = *(const shortx8*)&hin[(size_t)pr.x * H + f];
        #pragma unroll
        for (int j = 0; j < 8; ++j) acc[j] += w * b2f_s(r[j]);
    }
    #pragma unroll
    for (int j = 0; j < 8; ++j) acc[j] += __shfl_xor(acc[j], 32, 64);
    if (half == 0) {
        float4 bi0 = *(const float4*)&bias[f];
        float4 bi1 = *(const float4*)&bias[f + 4];
        shortx8 o;
        o[0] = (short)f2b(acc[0] + bi0.x);
        o[1] = (short)f2b(acc[1] + bi0.y);
        o[2] = (short)f2b(acc[2] + bi0.z);
        o[3] = (short)f2b(acc[3] + bi0.w);
        o[4] = (short)f2b(acc[4] + bi1.x);
        o[5] = (short)f2b(acc[5] + bi1.y);
        o[6] = (short)f2b(acc[6] + bi1.z);
        o[7] = (short)f2b(acc[7] + bi1.w);
        *(shortx8*)&hout[(size_t)node * H + f] = o;
    }
}

// ---------- conv1 variant: adds wsum * cvec (BN1 shift folded through A-hat) ----------
__global__ __launch_bounds__(256)
void k_agg_c(const unsigned short* __restrict__ hin, unsigned short* __restrict__ hout,
             const int* __restrict__ row_ptr, const int2* __restrict__ csr_sw,
             const float* __restrict__ dinv, const float* __restrict__ bias,
             const float* __restrict__ cvec, int N) {
    const int H = 256;
    int node = blockIdx.x * 4 + (threadIdx.x >> 6);
    if (node >= N) return;
    int lane = threadIdx.x & 63;
    int half = lane >> 5;
    int f = (lane & 31) * 8;
    float acc[8];
    float ws;
    float di = dinv[node];
    if (half == 0) {
        shortx8 hv = *(const shortx8*)&hin[(size_t)node * H + f];
        float sl = di * di;
        ws = sl;
        #pragma unroll
        for (int j = 0; j < 8; ++j) acc[j] = b2f_s(hv[j]) * sl;
    } else {
        ws = 0.f;
        #pragma unroll
        for (int j = 0; j < 8; ++j) acc[j] = 0.f;
    }
    int e0 = row_ptr[node], e1 = row_ptr[node + 1];
    int e = e0;
    for (; e + 8 <= e1; e += 8) {
        int2 p0 = csr_sw[e + 0 + half];
        int2 p1 = csr_sw[e + 2 + half];
        int2 p2 = csr_sw[e + 4 + half];
        int2 p3 = csr_sw[e + 6 + half];
        shortx8 r0 = *(const shortx8*)&hin[(size_t)p0.x * H + f];
        shortx8 r1 = *(const shortx8*)&hin[(size_t)p1.x * H + f];
        shortx8 r2 = *(const shortx8*)&hin[(size_t)p2.x * H + f];
        shortx8 r3 = *(const shortx8*)&hin[(size_t)p3.x * H + f];
        float w0 = __builtin_bit_cast(float, p0.y);
        float w1 = __builtin_bit_cast(float, p1.y);
        float w2 = __builtin_bit_cast(float, p2.y);
        float w3 = __builtin_bit_cast(float, p3.y);
        ws += (w0 + w1) + (w2 + w3);
        #pragma unroll
        for (int j = 0; j < 8; ++j)
            acc[j] += w0 * b2f_s(r0[j]) + w1 * b2f_s(r1[j])
                    + w2 * b2f_s(r2[j]) + w3 * b2f_s(r3[j]);
    }
    for (; e < e1; e += 2) {
        int idx = e + half;
        bool valid = idx < e1;
        int2 pr = csr_sw[valid ? idx : e];
        float w = valid ? __builtin_bit_cast(float, pr.y) : 0.f;
        shortx8 r = *(const shortx8*)&hin[(size_t)pr.x * H + f];
        ws += w;
        #pragma unroll
        for (int j = 0; j < 8; ++j) acc[j] += w * b2f_s(r[j]);
    }
    #pragma unroll
    for (int j = 0; j < 8; ++j) acc[j] += __shfl_xor(acc[j], 32, 64);
    ws += __shfl_xor(ws, 32, 64);
    if (half == 0) {
        float4 bi0 = *(const float4*)&bias[f];
        float4 bi1 = *(const float4*)&bias[f + 4];
        float4 c0 = *(const float4*)&cvec[f];
        float4 c1 = *(const float4*)&cvec[f + 4];
        bi0.x += ws * c0.x; bi0.y += ws * c0.y;
        bi0.z += ws * c0.z; bi0.w += ws * c0.w;
        bi1.x += ws * c1.x; bi1.y += ws * c1.y;
        bi1.z += ws * c1.z; bi1.w += ws * c1.w;
        shortx8 o;
        o[0] = (short)f2b(acc[0] + bi0.x);
        o[1] = (short)f2b(acc[1] + bi0.y);
        o[2] = (short)f2b(acc[2] + bi0.z);
        o[3] = (short)f2b(acc[3] + bi0.w);
        o[4] = (short)f2b(acc[4] + bi1.x);
        o[5] = (short)f2b(acc[5] + bi1.y);
        o[6] = (short)f2b(acc[6] + bi1.z);
        o[7] = (short)f2b(acc[7] + bi1.w);
        *(shortx8*)&hout[(size_t)node * H + f] = o;
    }
}

// ---------- head: BN2 affine + [256x5] dense + sigmoid, 4 nodes per block ----------
__global__ __launch_bounds__(256)
void k_head(const unsigned short* __restrict__ h, const float* __restrict__ a,
            const float* __restrict__ b, const float* __restrict__ Wd,
            const float* __restrict__ bd, float* __restrict__ out, int N) {
    int node = blockIdx.x * 4 + (threadIdx.x >> 6);
    if (node >= N) return;
    int lane = threadIdx.x & 63;
    int f = lane * 4;
    shortx4 hv = *(const shortx4*)&h[(size_t)node * 256 + f];
    float v0 = b2f_s(hv[0]) * a[f + 0] + b[f + 0];
    float v1 = b2f_s(hv[1]) * a[f + 1] + b[f + 1];
    float v2 = b2f_s(hv[2]) * a[f + 2] + b[f + 2];
    float v3 = b2f_s(hv[3]) * a[f + 3] + b[f + 3];
    float s[5];
    #pragma unroll
    for (int j = 0; j < 5; ++j) {
        s[j] = v0 * Wd[(f + 0) * 5 + j] + v1 * Wd[(f + 1) * 5 + j] +
               v2 * Wd[(f + 2) * 5 + j] + v3 * Wd[(f + 3) * 5 + j];
    }
    #pragma unroll
    for (int off = 32; off > 0; off >>= 1) {
        #pragma unroll
        for (int j = 0; j < 5; ++j) s[j] += __shfl_down(s[j], off, 64);
    }
    if (lane == 0) {
        #pragma unroll
        for (int j = 0; j < 5; ++j) {
            float z = s[j] + bd[j];
            out[(size_t)node * 5 + j] = 1.f / (1.f + expf(-z));
        }
    }
}

extern "C" void kernel_launch(void* const* d_in, const int* in_sizes, int n_in,
                              void* d_out, int out_size, void* d_ws, size_t ws_size,
                              hipStream_t stream) {
    const float* x      = (const float*)d_in[0];
    const void*  ei_raw = d_in[1];
    const float* gamma1 = (const float*)d_in[2];
    const float* beta1  = (const float*)d_in[3];
    const float* W1 = (const float*)d_in[4];
    const float* b1 = (const float*)d_in[5];
    const float* W2 = (const float*)d_in[6];
    const float* b2 = (const float*)d_in[7];
    const float* W3 = (const float*)d_in[8];
    const float* b3 = (const float*)d_in[9];
    const float* W4 = (const float*)d_in[10];
    const float* b4 = (const float*)d_in[11];
    const float* gamma2 = (const float*)d_in[12];
    const float* beta2  = (const float*)d_in[13];
    const float* Wd = (const float*)d_in[14];
    const float* bd = (const float*)d_in[15];

    const int F = in_sizes[2];        // 512
    const int N = in_sizes[0] / F;    // 50000
    const int E = in_sizes[1] / 2;    // 800000
    const int H = in_sizes[5];        // 256
    const int Mpad = ((N + 127) / 128) * 128;   // 50048
    const int NB   = (N + 1023) / 1024;
    float* out = (float*)d_out;

    char* p = (char*)d_ws;
    auto alloc = [&](size_t bytes) {
        void* r = (void*)p;
        p += (bytes + 255) & ~(size_t)255;
        return r;
    };
    int*   flag    = (int*)  alloc(4);
    // ---- contiguous zero-init group ----
    char*  zstart  = p;
    int*   cnt     = (int*)  alloc((size_t)N * 4);
    float* colsum8 = (float*)alloc((size_t)8 * F * 4);
    float* colsq8  = (float*)alloc((size_t)8 * F * 4);
    float* colsum2 = (float*)alloc((size_t)4 * H * 4);
    float* colsq2  = (float*)alloc((size_t)4 * H * 4);
    float* cvec    = (float*)alloc((size_t)H * 4);
    size_t zbytes  = (size_t)(p - zstart);
    int*   row_ptr = (int*)  alloc(((size_t)N + 1) * 4);
    int*   cursor  = (int*)  alloc((size_t)N * 4);
    float* dinv    = (float*)alloc((size_t)N * 4);
    int2*  csr_sw  = (int2*) alloc((size_t)E * 8);
    int*   bsum    = (int*)  alloc((size_t)NB * 4);
    float* bna     = (float*)alloc((size_t)F * 4);
    float* bnb     = (float*)alloc((size_t)F * 4);
    unsigned short* W1t = (unsigned short*)alloc((size_t)F * H * 2);
    unsigned short* W2t = (unsigned short*)alloc((size_t)H * H * 2);
    unsigned short* W3t = (unsigned short*)alloc((size_t)H * H * 2);
    unsigned short* W4t = (unsigned short*)alloc((size_t)H * H * 2);
    unsigned short* xb  = (unsigned short*)alloc((size_t)Mpad * F * 2);
    unsigned short* hbA = (unsigned short*)alloc((size_t)Mpad * H * 2);
    unsigned short* hbB = (unsigned short*)alloc((size_t)Mpad * H * 2);

    hipMemsetAsync(zstart, 0, zbytes, stream);
    hipMemsetAsync(xb + (size_t)N * F, 0, (size_t)(Mpad - N) * F * 2, stream);

    // graph build
    int n_check = (E >= 2048) ? 2048 : E;
    k_detect<<<1, 256, 0, stream>>>((const unsigned int*)ei_raw, n_check, flag);
    k_count<<<(E + 255) / 256, 256, 0, stream>>>(ei_raw, flag, cnt, E);
    k_scan_sum<<<NB, 1024, 0, stream>>>(cnt, bsum, N);
    k_scan_part<<<1, 1024, 0, stream>>>(bsum, NB);
    k_scan_final<<<NB, 1024, 0, stream>>>(cnt, bsum, row_ptr, cursor, dinv, N);
    k_fill<<<(E + 255) / 256, 256, 0, stream>>>(ei_raw, flag, cursor, dinv, csr_sw, E);

    // BN1 stats + raw cast (single pass over x)
    k_bnstats_cast<<<2048, 256, 0, stream>>>(x, xb, colsum8, colsq8, N, F);
    k_bnfin<<<(F + 255) / 256, 256, 0, stream>>>(colsum8, colsq8, gamma1, beta1, bna, bnb, N, F, 8);

    // weight prep (W1 scaled by bna) + cvec in one launch
    int tot = F * H + 3 * H * H;
    int wblocks = (tot + 255) / 256;
    k_prep_w<<<wblocks + 8, 256, 0, stream>>>(W1, W2, W3, W4, W1t, W2t, W3t, W4t,
                                              bna, bnb, cvec, F, H, wblocks);

    dim3 gg(Mpad / 128, H / 128);
    int aggb = (N + 3) / 4;
    // conv1 (BN1 folded: xb raw, W1t pre-scaled, cvec correction via wsum)
    k_gemm_bf16<<<gg, 256, 0, stream>>>(xb, W1t, hbA, F, H);
    k_agg_c<<<aggb, 256, 0, stream>>>(hbA, hbB, row_ptr, csr_sw, dinv, b1, cvec, N);
    // conv2
    k_gemm_bf16<<<gg, 256, 0, stream>>>(hbB, W2t, hbA, H, H);
    k_agg<<<aggb, 256, 0, stream>>>(hbA, hbB, row_ptr, csr_sw, dinv, b2, N);
    // conv3
    k_gemm_bf16<<<gg, 256, 0, stream>>>(hbB, W3t, hbA, H, H);
    k_agg<<<aggb, 256, 0, stream>>>(hbA, hbB, row_ptr, csr_sw, dinv, b3, N);
    // conv4
    k_gemm_bf16<<<gg, 256, 0, stream>>>(hbB, W4t, hbA, H, H);
    k_agg<<<aggb, 256, 0, stream>>>(hbA, hbB, row_ptr, csr_sw, dinv, b4, N);

    // BN2 + head
    k_bnstats_b<<<1024, 256, 0, stream>>>(hbB, colsum2, colsq2, N, H);
    k_bnfin<<<(H + 255) / 256, 256, 0, stream>>>(colsum2, colsq2, gamma2, beta2, bna, bnb, N, H, 4);
    k_head<<<(N + 3) / 4, 256, 0, stream>>>(hbB, bna, bnb, Wd, bd, out, N);
}

// Round 8
// 702.425 us; speedup vs baseline: 1.0142x; 1.0098x over previous
//
#include <hip/hip_runtime.h>
#include <math.h>

#define BN_EPS 1e-5f

typedef float floatx4 __attribute__((ext_vector_type(4)));
typedef short shortx4 __attribute__((ext_vector_type(4)));
typedef short shortx8 __attribute__((ext_vector_type(8)));
typedef __bf16 bf16x8 __attribute__((ext_vector_type(8)));

// ---- bf16 helpers ----
// f32 -> bf16 via hardware convert (RNE); compiler packs pairs into v_cvt_pk_bf16_f32.
__device__ __forceinline__ short f2bs(float f) {
    return __builtin_bit_cast(short, (__bf16)f);
}
__device__ __forceinline__ float b2f_s(short s) {
    unsigned int u = ((unsigned int)(unsigned short)s) << 16;
    return __builtin_bit_cast(float, u);
}

// ---------- edge-index layout detection (int32 vs int64 storage) ----------
__global__ __launch_bounds__(256)
void k_detect(const unsigned int* __restrict__ ei, int n_check, int* __restrict__ flag) {
    __shared__ int any;
    if (threadIdx.x == 0) any = 0;
    __syncthreads();
    for (int i = threadIdx.x; i < n_check; i += 256) {
        if (ei[2 * i + 1] != 0u) any = 1;
    }
    __syncthreads();
    if (threadIdx.x == 0) *flag = any;   // 1 => int32 layout, 0 => int64 layout
}

// ---------- degree count + per-edge slot sequence (ONE atomic pass total) ----------
__global__ __launch_bounds__(256)
void k_count_seq(const void* __restrict__ ei_raw, const int* __restrict__ flag,
                 int* __restrict__ cnt, int* __restrict__ seq, int E) {
    int e = blockIdx.x * 256 + threadIdx.x;
    if (e >= E) return;
    int d = (*flag) ? ((const int*)ei_raw)[E + e]
                    : (int)((const long long*)ei_raw)[E + e];
    seq[e] = atomicAdd(&cnt[d], 1);
}

// ---------- 3-phase parallel exclusive scan ----------
__global__ __launch_bounds__(1024)
void k_scan_sum(const int* __restrict__ cnt, int* __restrict__ bsum, int N) {
    __shared__ int s[1024];
    int i = blockIdx.x * 1024 + threadIdx.x;
    s[threadIdx.x] = (i < N) ? cnt[i] : 0;
    __syncthreads();
    for (int off = 512; off > 0; off >>= 1) {
        if (threadIdx.x < off) s[threadIdx.x] += s[threadIdx.x + off];
        __syncthreads();
    }
    if (threadIdx.x == 0) bsum[blockIdx.x] = s[0];
}

__global__ __launch_bounds__(1024)
void k_scan_part(int* __restrict__ bsum, int nb) {
    __shared__ int s[1024];
    int t = threadIdx.x;
    int v = (t < nb) ? bsum[t] : 0;
    s[t] = v;
    __syncthreads();
    for (int off = 1; off < 1024; off <<= 1) {
        int tmp = (t >= off) ? s[t - off] : 0;
        __syncthreads();
        s[t] += tmp;
        __syncthreads();
    }
    if (t < nb) bsum[t] = s[t] - v;     // exclusive
}

__global__ __launch_bounds__(1024)
void k_scan_final(const int* __restrict__ cnt, const int* __restrict__ bsum,
                  int* __restrict__ row_ptr, float* __restrict__ dinv, int N) {
    __shared__ int s[1024];
    int b = blockIdx.x, t = threadIdx.x;
    int i = b * 1024 + t;
    int v = (i < N) ? cnt[i] : 0;
    s[t] = v;
    __syncthreads();
    for (int off = 1; off < 1024; off <<= 1) {
        int tmp = (t >= off) ? s[t - off] : 0;
        __syncthreads();
        s[t] += tmp;
        __syncthreads();
    }
    if (i < N) {
        int excl = bsum[b] + s[t] - v;
        row_ptr[i] = excl;
        dinv[i] = rsqrtf((float)(v + 1));
        if (i == N - 1) row_ptr[N] = excl + v;
    }
}

// ---------- CSR place: p = row_ptr[dst] + seq[e]  (no atomics) ----------
__global__ __launch_bounds__(256)
void k_place(const void* __restrict__ ei_raw, const int* __restrict__ flag,
             const int* __restrict__ row_ptr, const int* __restrict__ seq,
             const float* __restrict__ dinv, int2* __restrict__ csr_sw, int E) {
    int e = blockIdx.x * 256 + threadIdx.x;
    if (e >= E) return;
    int s, d;
    if (*flag) {
        const int* a = (const int*)ei_raw;
        s = a[e]; d = a[E + e];
    } else {
        const long long* a = (const long long*)ei_raw;
        s = (int)a[e]; d = (int)a[E + e];
    }
    int p = row_ptr[d] + seq[e];
    float w = dinv[s] * dinv[d];
    csr_sw[p] = make_int2(s, __builtin_bit_cast(int, w));
}

// ---------- fused BN1 stats + raw bf16 cast of x (x read ONCE) ----------
// Thread owns 8 consecutive columns; 64 threads per row; 4 rows per block-pass.
__global__ __launch_bounds__(256)
void k_bnstats_cast(const float* __restrict__ x, unsigned short* __restrict__ xb,
                    float* __restrict__ sum8, float* __restrict__ sumsq8, int N, int F) {
    __shared__ float ls[512], lq[512];
    int t  = threadIdx.x;
    int cg = t & 63;             // 64 col-groups of 8 (F=512)
    int ro = t >> 6;             // 4 rows per pass
    int step = gridDim.x * 4;
    float s[8], q[8];
    #pragma unroll
    for (int j = 0; j < 8; ++j) { s[j] = 0.f; q[j] = 0.f; }
    size_t colb = (size_t)cg * 8;
    for (int r = blockIdx.x * 4 + ro; r < N; r += step) {
        float4 v0 = *(const float4*)&x[(size_t)r * F + colb];
        float4 v1 = *(const float4*)&x[(size_t)r * F + colb + 4];
        shortx8 o;
        o[0] = f2bs(v0.x); o[1] = f2bs(v0.y); o[2] = f2bs(v0.z); o[3] = f2bs(v0.w);
        o[4] = f2bs(v1.x); o[5] = f2bs(v1.y); o[6] = f2bs(v1.z); o[7] = f2bs(v1.w);
        *(shortx8*)&xb[(size_t)r * F + colb] = o;
        s[0] += v0.x; s[1] += v0.y; s[2] += v0.z; s[3] += v0.w;
        s[4] += v1.x; s[5] += v1.y; s[6] += v1.z; s[7] += v1.w;
        q[0] += v0.x * v0.x; q[1] += v0.y * v0.y; q[2] += v0.z * v0.z; q[3] += v0.w * v0.w;
        q[4] += v1.x * v1.x; q[5] += v1.y * v1.y; q[6] += v1.z * v1.z; q[7] += v1.w * v1.w;
    }
    ls[t] = 0.f; lq[t] = 0.f; ls[t + 256] = 0.f; lq[t + 256] = 0.f;
    __syncthreads();
    #pragma unroll
    for (int j = 0; j < 8; ++j) {
        atomicAdd(&ls[cg * 8 + j], s[j]);
        atomicAdd(&lq[cg * 8 + j], q[j]);
    }
    __syncthreads();
    int rep = (blockIdx.x & 7) * F;
    for (int c = t; c < F; c += 256) {
        atomicAdd(&sum8[rep + c],   ls[c]);
        atomicAdd(&sumsq8[rep + c], lq[c]);
    }
}

// ---------- batchnorm column stats on bf16 input (H=256), 4 replicas ----------
__global__ __launch_bounds__(256)
void k_bnstats_b(const unsigned short* __restrict__ x, float* __restrict__ sum,
                 float* __restrict__ sumsq, int N, int H) {
    __shared__ float ls[256], lq[256];
    int t  = threadIdx.x;
    int cg = t & 31;
    int ro = t >> 5;
    int step = gridDim.x * 8;
    float s[8], q[8];
    #pragma unroll
    for (int j = 0; j < 8; ++j) { s[j] = 0.f; q[j] = 0.f; }
    for (int r = blockIdx.x * 8 + ro; r < N; r += step) {
        shortx8 v = *(const shortx8*)&x[(size_t)r * H + cg * 8];
        #pragma unroll
        for (int j = 0; j < 8; ++j) {
            float f = b2f_s(v[j]);
            s[j] += f; q[j] += f * f;
        }
    }
    ls[t] = 0.f; lq[t] = 0.f;
    __syncthreads();
    #pragma unroll
    for (int j = 0; j < 8; ++j) {
        atomicAdd(&ls[cg * 8 + j], s[j]);
        atomicAdd(&lq[cg * 8 + j], q[j]);
    }
    __syncthreads();
    int rep = (blockIdx.x & 3) * H;
    atomicAdd(&sum[rep + t],   ls[t]);
    atomicAdd(&sumsq[rep + t], lq[t]);
}

// ---------- finalize BN affine from nrep replicated partials ----------
__global__ __launch_bounds__(256)
void k_bnfin(const float* __restrict__ sum, const float* __restrict__ sumsq,
             const float* __restrict__ gamma, const float* __restrict__ beta,
             float* __restrict__ a, float* __restrict__ b, int N, int F, int nrep) {
    int c = blockIdx.x * 256 + threadIdx.x;
    if (c >= F) return;
    float s = 0.f, ss = 0.f;
    for (int i = 0; i < nrep; ++i) { s += sum[i * F + c]; ss += sumsq[i * F + c]; }
    float m   = s / (float)N;
    float var = ss / (float)N - m * m;
    float rs  = rsqrtf(var + BN_EPS);
    float aa  = gamma[c] * rs;
    a[c] = aa;
    b[c] = beta[c] - m * aa;
}

// ---------- weight prep: cast+transpose all 4 W (W1 scaled by bna) + cvec tail-blocks ----------
__global__ __launch_bounds__(256)
void k_prep_w(const float* __restrict__ W1, const float* __restrict__ W2,
              const float* __restrict__ W3, const float* __restrict__ W4,
              unsigned short* __restrict__ T1, unsigned short* __restrict__ T2,
              unsigned short* __restrict__ T3, unsigned short* __restrict__ T4,
              const float* __restrict__ bna, const float* __restrict__ bnb,
              float* __restrict__ cvec, int F, int H, int wblocks) {
    if ((int)blockIdx.x >= wblocks) {
        // cvec: c_j = sum_k bnb[k] * W1[k,j]
        int bi = blockIdx.x - wblocks;       // 0..7
        int j = threadIdx.x;                 // H == 256
        int kslice = F / 8;
        int k0 = bi * kslice;
        float s = 0.f;
        for (int k = k0; k < k0 + kslice; ++k)
            s += bnb[k] * W1[(size_t)k * H + j];
        atomicAdd(&cvec[j], s);
        return;
    }
    int i = blockIdx.x * 256 + threadIdx.x;
    int n1 = F * H, n2 = H * H;
    if (i < n1) {
        int n = i / F, k = i % F;
        T1[i] = (unsigned short)f2bs(W1[(size_t)k * H + n] * bna[k]);
        return;
    }
    const float* W; unsigned short* T; int j;
    if (i < n1 + n2)          { W = W2; T = T2; j = i - n1; }
    else if (i < n1 + 2 * n2) { W = W3; T = T3; j = i - n1 - n2; }
    else if (i < n1 + 3 * n2) { W = W4; T = T4; j = i - n1 - 2 * n2; }
    else return;
    int n = j / H, k = j % H;
    T[j] = (unsigned short)f2bs(W[(size_t)k * H + n]);
}

// ---------- bf16 MFMA GEMM: C[M,NC] = A[M,K] @ Wt[NC,K]^T ----------
// Operand-swapped mfma -> C^T fragment layout -> 8B packed stores.
__device__ __forceinline__ void glds16(const void* g, void* l) {
    __builtin_amdgcn_global_load_lds(
        (const __attribute__((address_space(1))) unsigned int*)g,
        (__attribute__((address_space(3))) unsigned int*)l, 16, 0, 0);
}

__global__ __launch_bounds__(256)
void k_gemm_bf16(const unsigned short* __restrict__ A, const unsigned short* __restrict__ Bt,
                 unsigned short* __restrict__ C, int K, int NC) {
    __shared__ unsigned short As[128 * 32];
    __shared__ unsigned short Bs[128 * 32];
    int tid  = threadIdx.x;
    int wave = tid >> 6, lane = tid & 63;
    int row0 = blockIdx.x * 128;
    int col0 = blockIdx.y * 128;
    int wr = (wave & 1) * 64;
    int wc = (wave >> 1) * 64;

    floatx4 acc[4][4];
    #pragma unroll
    for (int i = 0; i < 4; i++)
        #pragma unroll
        for (int j = 0; j < 4; j++) acc[i][j] = (floatx4){0.f, 0.f, 0.f, 0.f};

    int cA = tid * 16;
    int cB = cA + 4096;
    const char* Ab = (const char*)A;
    const char* Bb = (const char*)Bt;
    size_t a_off0 = (size_t)(row0 + (cA >> 6)) * K * 2 + (cA & 63);
    size_t a_off1 = (size_t)(row0 + (cB >> 6)) * K * 2 + (cB & 63);
    size_t b_off0 = (size_t)(col0 + (cA >> 6)) * K * 2 + (cA & 63);
    size_t b_off1 = (size_t)(col0 + (cB >> 6)) * K * 2 + (cB & 63);

    int lm  = lane & 15;
    int lk8 = (lane >> 4) * 8;

    for (int ks = 0; ks < K; ks += 32) {
        size_t koff = (size_t)ks * 2;
        glds16(Ab + a_off0 + koff, (char*)As + cA);
        glds16(Ab + a_off1 + koff, (char*)As + cA + 4096);
        glds16(Bb + b_off0 + koff, (char*)Bs + cA);
        glds16(Bb + b_off1 + koff, (char*)Bs + cA + 4096);
        __syncthreads();

        bf16x8 af[4], bfr[4];
        #pragma unroll
        for (int i = 0; i < 4; i++) {
            shortx8 s = *(const shortx8*)&As[(wr + i * 16 + lm) * 32 + lk8];
            af[i] = __builtin_bit_cast(bf16x8, s);
        }
        #pragma unroll
        for (int j = 0; j < 4; j++) {
            shortx8 s = *(const shortx8*)&Bs[(wc + j * 16 + lm) * 32 + lk8];
            bfr[j] = __builtin_bit_cast(bf16x8, s);
        }
        // swapped operands: acc[i][j] holds C^T fragment
        #pragma unroll
        for (int i = 0; i < 4; i++)
            #pragma unroll
            for (int j = 0; j < 4; j++)
                acc[i][j] = __builtin_amdgcn_mfma_f32_16x16x32_bf16(bfr[j], af[i], acc[i][j], 0, 0, 0);
        __syncthreads();
    }

    // C^T layout: C-row = wr + i*16 + (lane&15); C-col = wc + j*16 + quad*4 + reg
    int quad = lane >> 4;
    int crow0 = row0 + wr + lm;
    int ccol0 = col0 + wc + quad * 4;
    #pragma unroll
    for (int i = 0; i < 4; i++) {
        size_t rbase = (size_t)(crow0 + i * 16) * NC;
        #pragma unroll
        for (int j = 0; j < 4; j++) {
            shortx4 o;
            o[0] = f2bs(acc[i][j][0]);
            o[1] = f2bs(acc[i][j][1]);
            o[2] = f2bs(acc[i][j][2]);
            o[3] = f2bs(acc[i][j][3]);
            *(shortx4*)&C[rbase + ccol0 + j * 16] = o;
        }
    }
}

// ---------- CSR gather-aggregation (8-edge main, predicated tail) ----------
// Wave per node, half-wave per edge slot, lane owns 8 features (16B loads).
__global__ __launch_bounds__(256)
void k_agg(const unsigned short* __restrict__ hin, unsigned short* __restrict__ hout,
           const int* __restrict__ row_ptr, const int2* __restrict__ csr_sw,
           const float* __restrict__ dinv, const float* __restrict__ bias, int N) {
    const int H = 256;
    int node = blockIdx.x * 4 + (threadIdx.x >> 6);
    if (node >= N) return;
    int lane = threadIdx.x & 63;
    int half = lane >> 5;
    int f = (lane & 31) * 8;
    float acc[8];
    float di = dinv[node];
    if (half == 0) {
        shortx8 hv = *(const shortx8*)&hin[(size_t)node * H + f];
        float sl = di * di;
        #pragma unroll
        for (int j = 0; j < 8; ++j) acc[j] = b2f_s(hv[j]) * sl;
    } else {
        #pragma unroll
        for (int j = 0; j < 8; ++j) acc[j] = 0.f;
    }
    int e0 = row_ptr[node], e1 = row_ptr[node + 1];
    int e = e0;
    for (; e + 8 <= e1; e += 8) {
        int2 p0 = csr_sw[e + 0 + half];
        int2 p1 = csr_sw[e + 2 + half];
        int2 p2 = csr_sw[e + 4 + half];
        int2 p3 = csr_sw[e + 6 + half];
        shortx8 r0 = *(const shortx8*)&hin[(size_t)p0.x * H + f];
        shortx8 r1 = *(const shortx8*)&hin[(size_t)p1.x * H + f];
        shortx8 r2 = *(const shortx8*)&hin[(size_t)p2.x * H + f];
        shortx8 r3 = *(const shortx8*)&hin[(size_t)p3.x * H + f];
        float w0 = __builtin_bit_cast(float, p0.y);
        float w1 = __builtin_bit_cast(float, p1.y);
        float w2 = __builtin_bit_cast(float, p2.y);
        float w3 = __builtin_bit_cast(float, p3.y);
        #pragma unroll
        for (int j = 0; j < 8; ++j)
            acc[j] += w0 * b2f_s(r0[j]) + w1 * b2f_s(r1[j])
                    + w2 * b2f_s(r2[j]) + w3 * b2f_s(r3[j]);
    }
    for (; e < e1; e += 2) {
        int idx = e + half;
        bool valid = idx < e1;
        int2 pr = csr_sw[valid ? idx : e];
        float w = valid ? __builtin_bit_cast(float, pr.y) : 0.f;
        shortx8 r = *(const shortx8*)&hin[(size_t)pr.x * H + f];
        #pragma unroll
        for (int j = 0; j < 8; ++j) acc[j] += w * b2f_s(r[j]);
    }
    #pragma unroll
    for (int j = 0; j < 8; ++j) acc[j] += __shfl_xor(acc[j], 32, 64);
    if (half == 0) {
        float4 bi0 = *(const float4*)&bias[f];
        float4 bi1 = *(const float4*)&bias[f + 4];
        shortx8 o;
        o[0] = f2bs(acc[0] + bi0.x);
        o[1] = f2bs(acc[1] + bi0.y);
        o[2] = f2bs(acc[2] + bi0.z);
        o[3] = f2bs(acc[3] + bi0.w);
        o[4] = f2bs(acc[4] + bi1.x);
        o[5] = f2bs(acc[5] + bi1.y);
        o[6] = f2bs(acc[6] + bi1.z);
        o[7] = f2bs(acc[7] + bi1.w);
        *(shortx8*)&hout[(size_t)node * H + f] = o;
    }
}

// ---------- conv1 variant: adds wsum * cvec (BN1 shift folded through A-hat) ----------
__global__ __launch_bounds__(256)
void k_agg_c(const unsigned short* __restrict__ hin, unsigned short* __restrict__ hout,
             const int* __restrict__ row_ptr, const int2* __restrict__ csr_sw,
             const float* __restrict__ dinv, const float* __restrict__ bias,
             const float* __restrict__ cvec, int N) {
    const int H = 256;
    int node = blockIdx.x * 4 + (threadIdx.x >> 6);
    if (node >= N) return;
    int lane = threadIdx.x & 63;
    int half = lane >> 5;
    int f = (lane & 31) * 8;
    float acc[8];
    float ws;
    float di = dinv[node];
    if (half == 0) {
        shortx8 hv = *(const shortx8*)&hin[(size_t)node * H + f];
        float sl = di * di;
        ws = sl;
        #pragma unroll
        for (int j = 0; j < 8; ++j) acc[j] = b2f_s(hv[j]) * sl;
    } else {
        ws = 0.f;
        #pragma unroll
        for (int j = 0; j < 8; ++j) acc[j] = 0.f;
    }
    int e0 = row_ptr[node], e1 = row_ptr[node + 1];
    int e = e0;
    for (; e + 8 <= e1; e += 8) {
        int2 p0 = csr_sw[e + 0 + half];
        int2 p1 = csr_sw[e + 2 + half];
        int2 p2 = csr_sw[e + 4 + half];
        int2 p3 = csr_sw[e + 6 + half];
        shortx8 r0 = *(const shortx8*)&hin[(size_t)p0.x * H + f];
        shortx8 r1 = *(const shortx8*)&hin[(size_t)p1.x * H + f];
        shortx8 r2 = *(const shortx8*)&hin[(size_t)p2.x * H + f];
        shortx8 r3 = *(const shortx8*)&hin[(size_t)p3.x * H + f];
        float w0 = __builtin_bit_cast(float, p0.y);
        float w1 = __builtin_bit_cast(float, p1.y);
        float w2 = __builtin_bit_cast(float, p2.y);
        float w3 = __builtin_bit_cast(float, p3.y);
        ws += (w0 + w1) + (w2 + w3);
        #pragma unroll
        for (int j = 0; j < 8; ++j)
            acc[j] += w0 * b2f_s(r0[j]) + w1 * b2f_s(r1[j])
                    + w2 * b2f_s(r2[j]) + w3 * b2f_s(r3[j]);
    }
    for (; e < e1; e += 2) {
        int idx = e + half;
        bool valid = idx < e1;
        int2 pr = csr_sw[valid ? idx : e];
        float w = valid ? __builtin_bit_cast(float, pr.y) : 0.f;
        shortx8 r = *(const shortx8*)&hin[(size_t)pr.x * H + f];
        ws += w;
        #pragma unroll
        for (int j = 0; j < 8; ++j) acc[j] += w * b2f_s(r[j]);
    }
    #pragma unroll
    for (int j = 0; j < 8; ++j) acc[j] += __shfl_xor(acc[j], 32, 64);
    ws += __shfl_xor(ws, 32, 64);
    if (half == 0) {
        float4 bi0 = *(const float4*)&bias[f];
        float4 bi1 = *(const float4*)&bias[f + 4];
        float4 c0 = *(const float4*)&cvec[f];
        float4 c1 = *(const float4*)&cvec[f + 4];
        bi0.x += ws * c0.x; bi0.y += ws * c0.y;
        bi0.z += ws * c0.z; bi0.w += ws * c0.w;
        bi1.x += ws * c1.x; bi1.y += ws * c1.y;
        bi1.z += ws * c1.z; bi1.w += ws * c1.w;
        shortx8 o;
        o[0] = f2bs(acc[0] + bi0.x);
        o[1] = f2bs(acc[1] + bi0.y);
        o[2] = f2bs(acc[2] + bi0.z);
        o[3] = f2bs(acc[3] + bi0.w);
        o[4] = f2bs(acc[4] + bi1.x);
        o[5] = f2bs(acc[5] + bi1.y);
        o[6] = f2bs(acc[6] + bi1.z);
        o[7] = f2bs(acc[7] + bi1.w);
        *(shortx8*)&hout[(size_t)node * H + f] = o;
    }
}

// ---------- head: BN2 affine + [256x5] dense + sigmoid, 4 nodes per block ----------
__global__ __launch_bounds__(256)
void k_head(const unsigned short* __restrict__ h, const float* __restrict__ a,
            const float* __restrict__ b, const float* __restrict__ Wd,
            const float* __restrict__ bd, float* __restrict__ out, int N) {
    int node = blockIdx.x * 4 + (threadIdx.x >> 6);
    if (node >= N) return;
    int lane = threadIdx.x & 63;
    int f = lane * 4;
    shortx4 hv = *(const shortx4*)&h[(size_t)node * 256 + f];
    float v0 = b2f_s(hv[0]) * a[f + 0] + b[f + 0];
    float v1 = b2f_s(hv[1]) * a[f + 1] + b[f + 1];
    float v2 = b2f_s(hv[2]) * a[f + 2] + b[f + 2];
    float v3 = b2f_s(hv[3]) * a[f + 3] + b[f + 3];
    float s[5];
    #pragma unroll
    for (int j = 0; j < 5; ++j) {
        s[j] = v0 * Wd[(f + 0) * 5 + j] + v1 * Wd[(f + 1) * 5 + j] +
               v2 * Wd[(f + 2) * 5 + j] + v3 * Wd[(f + 3) * 5 + j];
    }
    #pragma unroll
    for (int off = 32; off > 0; off >>= 1) {
        #pragma unroll
        for (int j = 0; j < 5; ++j) s[j] += __shfl_down(s[j], off, 64);
    }
    if (lane == 0) {
        #pragma unroll
        for (int j = 0; j < 5; ++j) {
            float z = s[j] + bd[j];
            out[(size_t)node * 5 + j] = 1.f / (1.f + expf(-z));
        }
    }
}

extern "C" void kernel_launch(void* const* d_in, const int* in_sizes, int n_in,
                              void* d_out, int out_size, void* d_ws, size_t ws_size,
                              hipStream_t stream) {
    const float* x      = (const float*)d_in[0];
    const void*  ei_raw = d_in[1];
    const float* gamma1 = (const float*)d_in[2];
    const float* beta1  = (const float*)d_in[3];
    const float* W1 = (const float*)d_in[4];
    const float* b1 = (const float*)d_in[5];
    const float* W2 = (const float*)d_in[6];
    const float* b2 = (const float*)d_in[7];
    const float* W3 = (const float*)d_in[8];
    const float* b3 = (const float*)d_in[9];
    const float* W4 = (const float*)d_in[10];
    const float* b4 = (const float*)d_in[11];
    const float* gamma2 = (const float*)d_in[12];
    const float* beta2  = (const float*)d_in[13];
    const float* Wd = (const float*)d_in[14];
    const float* bd = (const float*)d_in[15];

    const int F = in_sizes[2];        // 512
    const int N = in_sizes[0] / F;    // 50000
    const int E = in_sizes[1] / 2;    // 800000
    const int H = in_sizes[5];        // 256
    const int Mpad = ((N + 127) / 128) * 128;   // 50048
    const int NB   = (N + 1023) / 1024;
    float* out = (float*)d_out;

    char* p = (char*)d_ws;
    auto alloc = [&](size_t bytes) {
        void* r = (void*)p;
        p += (bytes + 255) & ~(size_t)255;
        return r;
    };
    int*   flag    = (int*)  alloc(4);
    // ---- contiguous zero-init group ----
    char*  zstart  = p;
    int*   cnt     = (int*)  alloc((size_t)N * 4);
    float* colsum8 = (float*)alloc((size_t)8 * F * 4);
    float* colsq8  = (float*)alloc((size_t)8 * F * 4);
    float* colsum2 = (float*)alloc((size_t)4 * H * 4);
    float* colsq2  = (float*)alloc((size_t)4 * H * 4);
    float* cvec    = (float*)alloc((size_t)H * 4);
    size_t zbytes  = (size_t)(p - zstart);
    int*   row_ptr = (int*)  alloc(((size_t)N + 1) * 4);
    int*   seq     = (int*)  alloc((size_t)E * 4);
    float* dinv    = (float*)alloc((size_t)N * 4);
    int2*  csr_sw  = (int2*) alloc((size_t)E * 8);
    int*   bsum    = (int*)  alloc((size_t)NB * 4);
    float* bna     = (float*)alloc((size_t)F * 4);
    float* bnb     = (float*)alloc((size_t)F * 4);
    unsigned short* W1t = (unsigned short*)alloc((size_t)F * H * 2);
    unsigned short* W2t = (unsigned short*)alloc((size_t)H * H * 2);
    unsigned short* W3t = (unsigned short*)alloc((size_t)H * H * 2);
    unsigned short* W4t = (unsigned short*)alloc((size_t)H * H * 2);
    unsigned short* xb  = (unsigned short*)alloc((size_t)Mpad * F * 2);
    unsigned short* hbA = (unsigned short*)alloc((size_t)Mpad * H * 2);
    unsigned short* hbB = (unsigned short*)alloc((size_t)Mpad * H * 2);

    hipMemsetAsync(zstart, 0, zbytes, stream);
    hipMemsetAsync(xb + (size_t)N * F, 0, (size_t)(Mpad - N) * F * 2, stream);

    // graph build (single atomic pass: count+seq, then scan, then place)
    int n_check = (E >= 2048) ? 2048 : E;
    k_detect<<<1, 256, 0, stream>>>((const unsigned int*)ei_raw, n_check, flag);
    k_count_seq<<<(E + 255) / 256, 256, 0, stream>>>(ei_raw, flag, cnt, seq, E);
    k_scan_sum<<<NB, 1024, 0, stream>>>(cnt, bsum, N);
    k_scan_part<<<1, 1024, 0, stream>>>(bsum, NB);
    k_scan_final<<<NB, 1024, 0, stream>>>(cnt, bsum, row_ptr, dinv, N);
    k_place<<<(E + 255) / 256, 256, 0, stream>>>(ei_raw, flag, row_ptr, seq, dinv, csr_sw, E);

    // BN1 stats + raw cast (single pass over x)
    k_bnstats_cast<<<2048, 256, 0, stream>>>(x, xb, colsum8, colsq8, N, F);
    k_bnfin<<<(F + 255) / 256, 256, 0, stream>>>(colsum8, colsq8, gamma1, beta1, bna, bnb, N, F, 8);

    // weight prep (W1 scaled by bna) + cvec in one launch
    int tot = F * H + 3 * H * H;
    int wblocks = (tot + 255) / 256;
    k_prep_w<<<wblocks + 8, 256, 0, stream>>>(W1, W2, W3, W4, W1t, W2t, W3t, W4t,
                                              bna, bnb, cvec, F, H, wblocks);

    dim3 gg(Mpad / 128, H / 128);
    int aggb = (N + 3) / 4;
    // conv1 (BN1 folded: xb raw, W1t pre-scaled, cvec correction via wsum)
    k_gemm_bf16<<<gg, 256, 0, stream>>>(xb, W1t, hbA, F, H);
    k_agg_c<<<aggb, 256, 0, stream>>>(hbA, hbB, row_ptr, csr_sw, dinv, b1, cvec, N);
    // conv2
    k_gemm_bf16<<<gg, 256, 0, stream>>>(hbB, W2t, hbA, H, H);
    k_agg<<<aggb, 256, 0, stream>>>(hbA, hbB, row_ptr, csr_sw, dinv, b2, N);
    // conv3
    k_gemm_bf16<<<gg, 256, 0, stream>>>(hbB, W3t, hbA, H, H);
    k_agg<<<aggb, 256, 0, stream>>>(hbA, hbB, row_ptr, csr_sw, dinv, b3, N);
    // conv4
    k_gemm_bf16<<<gg, 256, 0, stream>>>(hbB, W4t, hbA, H, H);
    k_agg<<<aggb, 256, 0, stream>>>(hbA, hbB, row_ptr, csr_sw, dinv, b4, N);

    // BN2 + head
    k_bnstats_b<<<1024, 256, 0, stream>>>(hbB, colsum2, colsq2, N, H);
    k_bnfin<<<(H + 255) / 256, 256, 0, stream>>>(colsum2, colsq2, gamma2, beta2, bna, bnb, N, H, 4);
    k_head<<<(N + 3) / 4, 256, 0, stream>>>(hbB, bna, bnb, Wd, bd, out, N);
}

// Round 9
// 702.265 us; speedup vs baseline: 1.0145x; 1.0002x over previous
//
#include <hip/hip_runtime.h>
#include <math.h>

#define BN_EPS 1e-5f

typedef float floatx4 __attribute__((ext_vector_type(4)));
typedef short shortx4 __attribute__((ext_vector_type(4)));
typedef short shortx8 __attribute__((ext_vector_type(8)));
typedef __bf16 bf16x8 __attribute__((ext_vector_type(8)));

// ---- bf16 helpers ----
__device__ __forceinline__ short f2bs(float f) {
    return __builtin_bit_cast(short, (__bf16)f);   // hw v_cvt RNE
}
__device__ __forceinline__ float b2f_s(short s) {
    unsigned int u = ((unsigned int)(unsigned short)s) << 16;
    return __builtin_bit_cast(float, u);
}

// ---------- edge-index layout detection (int32 vs int64 storage) ----------
__global__ __launch_bounds__(256)
void k_detect(const unsigned int* __restrict__ ei, int n_check, int* __restrict__ flag) {
    __shared__ int any;
    if (threadIdx.x == 0) any = 0;
    __syncthreads();
    for (int i = threadIdx.x; i < n_check; i += 256) {
        if (ei[2 * i + 1] != 0u) any = 1;
    }
    __syncthreads();
    if (threadIdx.x == 0) *flag = any;   // 1 => int32 layout, 0 => int64 layout
}

// ---------- degree count + per-edge slot sequence (ONE atomic pass total) ----------
__global__ __launch_bounds__(256)
void k_count_seq(const void* __restrict__ ei_raw, const int* __restrict__ flag,
                 int* __restrict__ cnt, int* __restrict__ seq, int E) {
    int e = blockIdx.x * 256 + threadIdx.x;
    if (e >= E) return;
    int d = (*flag) ? ((const int*)ei_raw)[E + e]
                    : (int)((const long long*)ei_raw)[E + e];
    seq[e] = atomicAdd(&cnt[d], 1);
}

// ---------- 3-phase parallel exclusive scan ----------
__global__ __launch_bounds__(1024)
void k_scan_sum(const int* __restrict__ cnt, int* __restrict__ bsum, int N) {
    __shared__ int s[1024];
    int i = blockIdx.x * 1024 + threadIdx.x;
    s[threadIdx.x] = (i < N) ? cnt[i] : 0;
    __syncthreads();
    for (int off = 512; off > 0; off >>= 1) {
        if (threadIdx.x < off) s[threadIdx.x] += s[threadIdx.x + off];
        __syncthreads();
    }
    if (threadIdx.x == 0) bsum[blockIdx.x] = s[0];
}

__global__ __launch_bounds__(1024)
void k_scan_part(int* __restrict__ bsum, int nb) {
    __shared__ int s[1024];
    int t = threadIdx.x;
    int v = (t < nb) ? bsum[t] : 0;
    s[t] = v;
    __syncthreads();
    for (int off = 1; off < 1024; off <<= 1) {
        int tmp = (t >= off) ? s[t - off] : 0;
        __syncthreads();
        s[t] += tmp;
        __syncthreads();
    }
    if (t < nb) bsum[t] = s[t] - v;     // exclusive
}

__global__ __launch_bounds__(1024)
void k_scan_final(const int* __restrict__ cnt, const int* __restrict__ bsum,
                  int* __restrict__ row_ptr, float* __restrict__ dinv, int N) {
    __shared__ int s[1024];
    int b = blockIdx.x, t = threadIdx.x;
    int i = b * 1024 + t;
    int v = (i < N) ? cnt[i] : 0;
    s[t] = v;
    __syncthreads();
    for (int off = 1; off < 1024; off <<= 1) {
        int tmp = (t >= off) ? s[t - off] : 0;
        __syncthreads();
        s[t] += tmp;
        __syncthreads();
    }
    if (i < N) {
        int excl = bsum[b] + s[t] - v;
        row_ptr[i] = excl;
        dinv[i] = rsqrtf((float)(v + 1));
        if (i == N - 1) row_ptr[N] = excl + v;
    }
}

// ---------- CSR place: p = row_ptr[dst] + seq[e]  (no atomics) ----------
__global__ __launch_bounds__(256)
void k_place(const void* __restrict__ ei_raw, const int* __restrict__ flag,
             const int* __restrict__ row_ptr, const int* __restrict__ seq,
             const float* __restrict__ dinv, int2* __restrict__ csr_sw, int E) {
    int e = blockIdx.x * 256 + threadIdx.x;
    if (e >= E) return;
    int s, d;
    if (*flag) {
        const int* a = (const int*)ei_raw;
        s = a[e]; d = a[E + e];
    } else {
        const long long* a = (const long long*)ei_raw;
        s = (int)a[e]; d = (int)a[E + e];
    }
    int p = row_ptr[d] + seq[e];
    float w = dinv[s] * dinv[d];
    csr_sw[p] = make_int2(s, __builtin_bit_cast(int, w));
}

// ---------- fused BN1 stats + raw bf16 cast of x (x read ONCE) ----------
// Thread owns 8 consecutive columns; 64 threads/row; 4 independent rows in flight.
__global__ __launch_bounds__(256)
void k_bnstats_cast(const float* __restrict__ x, unsigned short* __restrict__ xb,
                    float* __restrict__ sum8, float* __restrict__ sumsq8, int N, int F) {
    __shared__ float ls[512], lq[512];
    int t  = threadIdx.x;
    int cg = t & 63;             // 64 col-groups of 8 (F=512)
    int ro = t >> 6;             // 4 rows per pass
    int step = gridDim.x * 4;
    float s[8], q[8];
    #pragma unroll
    for (int j = 0; j < 8; ++j) { s[j] = 0.f; q[j] = 0.f; }
    size_t colb = (size_t)cg * 8;
    for (int r = blockIdx.x * 4 + ro; r < N; r += 4 * step) {
        int rb = r + step, rc = r + 2 * step, rd = r + 3 * step;
        bool ob = rb < N, oc = rc < N, od = rd < N;
        // issue all loads first (up to 8 float4 in flight)
        float4 a0 = *(const float4*)&x[(size_t)r * F + colb];
        float4 a1 = *(const float4*)&x[(size_t)r * F + colb + 4];
        float4 b0, b1, c0, c1, d0, d1;
        if (ob) { b0 = *(const float4*)&x[(size_t)rb * F + colb];
                  b1 = *(const float4*)&x[(size_t)rb * F + colb + 4]; }
        if (oc) { c0 = *(const float4*)&x[(size_t)rc * F + colb];
                  c1 = *(const float4*)&x[(size_t)rc * F + colb + 4]; }
        if (od) { d0 = *(const float4*)&x[(size_t)rd * F + colb];
                  d1 = *(const float4*)&x[(size_t)rd * F + colb + 4]; }
        shortx8 o;
        o[0] = f2bs(a0.x); o[1] = f2bs(a0.y); o[2] = f2bs(a0.z); o[3] = f2bs(a0.w);
        o[4] = f2bs(a1.x); o[5] = f2bs(a1.y); o[6] = f2bs(a1.z); o[7] = f2bs(a1.w);
        *(shortx8*)&xb[(size_t)r * F + colb] = o;
        s[0] += a0.x; s[1] += a0.y; s[2] += a0.z; s[3] += a0.w;
        s[4] += a1.x; s[5] += a1.y; s[6] += a1.z; s[7] += a1.w;
        q[0] += a0.x * a0.x; q[1] += a0.y * a0.y; q[2] += a0.z * a0.z; q[3] += a0.w * a0.w;
        q[4] += a1.x * a1.x; q[5] += a1.y * a1.y; q[6] += a1.z * a1.z; q[7] += a1.w * a1.w;
        if (ob) {
            o[0] = f2bs(b0.x); o[1] = f2bs(b0.y); o[2] = f2bs(b0.z); o[3] = f2bs(b0.w);
            o[4] = f2bs(b1.x); o[5] = f2bs(b1.y); o[6] = f2bs(b1.z); o[7] = f2bs(b1.w);
            *(shortx8*)&xb[(size_t)rb * F + colb] = o;
            s[0] += b0.x; s[1] += b0.y; s[2] += b0.z; s[3] += b0.w;
            s[4] += b1.x; s[5] += b1.y; s[6] += b1.z; s[7] += b1.w;
            q[0] += b0.x * b0.x; q[1] += b0.y * b0.y; q[2] += b0.z * b0.z; q[3] += b0.w * b0.w;
            q[4] += b1.x * b1.x; q[5] += b1.y * b1.y; q[6] += b1.z * b1.z; q[7] += b1.w * b1.w;
        }
        if (oc) {
            o[0] = f2bs(c0.x); o[1] = f2bs(c0.y); o[2] = f2bs(c0.z); o[3] = f2bs(c0.w);
            o[4] = f2bs(c1.x); o[5] = f2bs(c1.y); o[6] = f2bs(c1.z); o[7] = f2bs(c1.w);
            *(shortx8*)&xb[(size_t)rc * F + colb] = o;
            s[0] += c0.x; s[1] += c0.y; s[2] += c0.z; s[3] += c0.w;
            s[4] += c1.x; s[5] += c1.y; s[6] += c1.z; s[7] += c1.w;
            q[0] += c0.x * c0.x; q[1] += c0.y * c0.y; q[2] += c0.z * c0.z; q[3] += c0.w * c0.w;
            q[4] += c1.x * c1.x; q[5] += c1.y * c1.y; q[6] += c1.z * c1.z; q[7] += c1.w * c1.w;
        }
        if (od) {
            o[0] = f2bs(d0.x); o[1] = f2bs(d0.y); o[2] = f2bs(d0.z); o[3] = f2bs(d0.w);
            o[4] = f2bs(d1.x); o[5] = f2bs(d1.y); o[6] = f2bs(d1.z); o[7] = f2bs(d1.w);
            *(shortx8*)&xb[(size_t)rd * F + colb] = o;
            s[0] += d0.x; s[1] += d0.y; s[2] += d0.z; s[3] += d0.w;
            s[4] += d1.x; s[5] += d1.y; s[6] += d1.z; s[7] += d1.w;
            q[0] += d0.x * d0.x; q[1] += d0.y * d0.y; q[2] += d0.z * d0.z; q[3] += d0.w * d0.w;
            q[4] += d1.x * d1.x; q[5] += d1.y * d1.y; q[6] += d1.z * d1.z; q[7] += d1.w * d1.w;
        }
    }
    ls[t] = 0.f; lq[t] = 0.f; ls[t + 256] = 0.f; lq[t + 256] = 0.f;
    __syncthreads();
    #pragma unroll
    for (int j = 0; j < 8; ++j) {
        atomicAdd(&ls[cg * 8 + j], s[j]);
        atomicAdd(&lq[cg * 8 + j], q[j]);
    }
    __syncthreads();
    int rep = (blockIdx.x & 7) * F;
    for (int c = t; c < F; c += 256) {
        atomicAdd(&sum8[rep + c],   ls[c]);
        atomicAdd(&sumsq8[rep + c], lq[c]);
    }
}

// ---------- batchnorm column stats on bf16 input (H=256), 4 replicas ----------
__global__ __launch_bounds__(256)
void k_bnstats_b(const unsigned short* __restrict__ x, float* __restrict__ sum,
                 float* __restrict__ sumsq, int N, int H) {
    __shared__ float ls[256], lq[256];
    int t  = threadIdx.x;
    int cg = t & 31;
    int ro = t >> 5;
    int step = gridDim.x * 8;
    float s[8], q[8];
    #pragma unroll
    for (int j = 0; j < 8; ++j) { s[j] = 0.f; q[j] = 0.f; }
    for (int r = blockIdx.x * 8 + ro; r < N; r += step) {
        shortx8 v = *(const shortx8*)&x[(size_t)r * H + cg * 8];
        #pragma unroll
        for (int j = 0; j < 8; ++j) {
            float f = b2f_s(v[j]);
            s[j] += f; q[j] += f * f;
        }
    }
    ls[t] = 0.f; lq[t] = 0.f;
    __syncthreads();
    #pragma unroll
    for (int j = 0; j < 8; ++j) {
        atomicAdd(&ls[cg * 8 + j], s[j]);
        atomicAdd(&lq[cg * 8 + j], q[j]);
    }
    __syncthreads();
    int rep = (blockIdx.x & 3) * H;
    atomicAdd(&sum[rep + t],   ls[t]);
    atomicAdd(&sumsq[rep + t], lq[t]);
}

// ---------- finalize BN affine from nrep replicated partials ----------
__global__ __launch_bounds__(256)
void k_bnfin(const float* __restrict__ sum, const float* __restrict__ sumsq,
             const float* __restrict__ gamma, const float* __restrict__ beta,
             float* __restrict__ a, float* __restrict__ b, int N, int F, int nrep) {
    int c = blockIdx.x * 256 + threadIdx.x;
    if (c >= F) return;
    float s = 0.f, ss = 0.f;
    for (int i = 0; i < nrep; ++i) { s += sum[i * F + c]; ss += sumsq[i * F + c]; }
    float m   = s / (float)N;
    float var = ss / (float)N - m * m;
    float rs  = rsqrtf(var + BN_EPS);
    float aa  = gamma[c] * rs;
    a[c] = aa;
    b[c] = beta[c] - m * aa;
}

// ---------- fold BN2 affine into head weights: Wd'[f][j]=a[f]*Wd[f][j]; bd'[j]=bd[j]+sum_f b[f]*Wd[f][j] ----------
__global__ __launch_bounds__(256)
void k_prep_hd(const float* __restrict__ Wd, const float* __restrict__ bd,
               const float* __restrict__ a, const float* __restrict__ b,
               float* __restrict__ Wdp, float* __restrict__ bdp, int H) {
    __shared__ float ls[5];
    int f = threadIdx.x;           // H == 256
    if (f < 5) ls[f] = 0.f;
    __syncthreads();
    float af = a[f], bf = b[f];
    float w[5];
    #pragma unroll
    for (int j = 0; j < 5; ++j) {
        float wv = Wd[f * 5 + j];
        w[j] = af * wv;
        atomicAdd(&ls[j], bf * wv);
    }
    #pragma unroll
    for (int j = 0; j < 5; ++j) Wdp[f * 5 + j] = w[j];
    __syncthreads();
    if (f < 5) bdp[f] = bd[f] + ls[f];
}

// ---------- weight prep: cast+transpose all 4 W (W1 scaled by bna) + cvec tail-blocks ----------
__global__ __launch_bounds__(256)
void k_prep_w(const float* __restrict__ W1, const float* __restrict__ W2,
              const float* __restrict__ W3, const float* __restrict__ W4,
              unsigned short* __restrict__ T1, unsigned short* __restrict__ T2,
              unsigned short* __restrict__ T3, unsigned short* __restrict__ T4,
              const float* __restrict__ bna, const float* __restrict__ bnb,
              float* __restrict__ cvec, int F, int H, int wblocks) {
    if ((int)blockIdx.x >= wblocks) {
        int bi = blockIdx.x - wblocks;       // 0..7
        int j = threadIdx.x;                 // H == 256
        int kslice = F / 8;
        int k0 = bi * kslice;
        float s = 0.f;
        for (int k = k0; k < k0 + kslice; ++k)
            s += bnb[k] * W1[(size_t)k * H + j];
        atomicAdd(&cvec[j], s);
        return;
    }
    int i = blockIdx.x * 256 + threadIdx.x;
    int n1 = F * H, n2 = H * H;
    if (i < n1) {
        int n = i / F, k = i % F;
        T1[i] = (unsigned short)f2bs(W1[(size_t)k * H + n] * bna[k]);
        return;
    }
    const float* W; unsigned short* T; int j;
    if (i < n1 + n2)          { W = W2; T = T2; j = i - n1; }
    else if (i < n1 + 2 * n2) { W = W3; T = T3; j = i - n1 - n2; }
    else if (i < n1 + 3 * n2) { W = W4; T = T4; j = i - n1 - 2 * n2; }
    else return;
    int n = j / H, k = j % H;
    T[j] = (unsigned short)f2bs(W[(size_t)k * H + n]);
}

// ---------- bf16 MFMA GEMM: C[M,NC] = A[M,K] @ Wt[NC,K]^T ----------
__device__ __forceinline__ void glds16(const void* g, void* l) {
    __builtin_amdgcn_global_load_lds(
        (const __attribute__((address_space(1))) unsigned int*)g,
        (__attribute__((address_space(3))) unsigned int*)l, 16, 0, 0);
}

__global__ __launch_bounds__(256)
void k_gemm_bf16(const unsigned short* __restrict__ A, const unsigned short* __restrict__ Bt,
                 unsigned short* __restrict__ C, int K, int NC) {
    __shared__ unsigned short As[128 * 32];
    __shared__ unsigned short Bs[128 * 32];
    int tid  = threadIdx.x;
    int wave = tid >> 6, lane = tid & 63;
    int row0 = blockIdx.x * 128;
    int col0 = blockIdx.y * 128;
    int wr = (wave & 1) * 64;
    int wc = (wave >> 1) * 64;

    floatx4 acc[4][4];
    #pragma unroll
    for (int i = 0; i < 4; i++)
        #pragma unroll
        for (int j = 0; j < 4; j++) acc[i][j] = (floatx4){0.f, 0.f, 0.f, 0.f};

    int cA = tid * 16;
    int cB = cA + 4096;
    const char* Ab = (const char*)A;
    const char* Bb = (const char*)Bt;
    size_t a_off0 = (size_t)(row0 + (cA >> 6)) * K * 2 + (cA & 63);
    size_t a_off1 = (size_t)(row0 + (cB >> 6)) * K * 2 + (cB & 63);
    size_t b_off0 = (size_t)(col0 + (cA >> 6)) * K * 2 + (cA & 63);
    size_t b_off1 = (size_t)(col0 + (cB >> 6)) * K * 2 + (cB & 63);

    int lm  = lane & 15;
    int lk8 = (lane >> 4) * 8;

    for (int ks = 0; ks < K; ks += 32) {
        size_t koff = (size_t)ks * 2;
        glds16(Ab + a_off0 + koff, (char*)As + cA);
        glds16(Ab + a_off1 + koff, (char*)As + cA + 4096);
        glds16(Bb + b_off0 + koff, (char*)Bs + cA);
        glds16(Bb + b_off1 + koff, (char*)Bs + cA + 4096);
        __syncthreads();

        bf16x8 af[4], bfr[4];
        #pragma unroll
        for (int i = 0; i < 4; i++) {
            shortx8 s = *(const shortx8*)&As[(wr + i * 16 + lm) * 32 + lk8];
            af[i] = __builtin_bit_cast(bf16x8, s);
        }
        #pragma unroll
        for (int j = 0; j < 4; j++) {
            shortx8 s = *(const shortx8*)&Bs[(wc + j * 16 + lm) * 32 + lk8];
            bfr[j] = __builtin_bit_cast(bf16x8, s);
        }
        // swapped operands: acc[i][j] holds C^T fragment
        #pragma unroll
        for (int i = 0; i < 4; i++)
            #pragma unroll
            for (int j = 0; j < 4; j++)
                acc[i][j] = __builtin_amdgcn_mfma_f32_16x16x32_bf16(bfr[j], af[i], acc[i][j], 0, 0, 0);
        __syncthreads();
    }

    int quad = lane >> 4;
    int crow0 = row0 + wr + lm;
    int ccol0 = col0 + wc + quad * 4;
    #pragma unroll
    for (int i = 0; i < 4; i++) {
        size_t rbase = (size_t)(crow0 + i * 16) * NC;
        #pragma unroll
        for (int j = 0; j < 4; j++) {
            shortx4 o;
            o[0] = f2bs(acc[i][j][0]);
            o[1] = f2bs(acc[i][j][1]);
            o[2] = f2bs(acc[i][j][2]);
            o[3] = f2bs(acc[i][j][3]);
            *(shortx4*)&C[rbase + ccol0 + j * 16] = o;
        }
    }
}

// ---------- CSR gather-aggregation (8-edge main, predicated tail) ----------
__global__ __launch_bounds__(256)
void k_agg(const unsigned short* __restrict__ hin, unsigned short* __restrict__ hout,
           const int* __restrict__ row_ptr, const int2* __restrict__ csr_sw,
           const float* __restrict__ dinv, const float* __restrict__ bias, int N) {
    const int H = 256;
    int node = blockIdx.x * 4 + (threadIdx.x >> 6);
    if (node >= N) return;
    int lane = threadIdx.x & 63;
    int half = lane >> 5;
    int f = (lane & 31) * 8;
    float acc[8];
    float di = dinv[node];
    if (half == 0) {
        shortx8 hv = *(const shortx8*)&hin[(size_t)node * H + f];
        float sl = di * di;
        #pragma unroll
        for (int j = 0; j < 8; ++j) acc[j] = b2f_s(hv[j]) * sl;
    } else {
        #pragma unroll
        for (int j = 0; j < 8; ++j) acc[j] = 0.f;
    }
    int e0 = row_ptr[node], e1 = row_ptr[node + 1];
    int e = e0;
    for (; e + 8 <= e1; e += 8) {
        int2 p0 = csr_sw[e + 0 + half];
        int2 p1 = csr_sw[e + 2 + half];
        int2 p2 = csr_sw[e + 4 + half];
        int2 p3 = csr_sw[e + 6 + half];
        shortx8 r0 = *(const shortx8*)&hin[(size_t)p0.x * H + f];
        shortx8 r1 = *(const shortx8*)&hin[(size_t)p1.x * H + f];
        shortx8 r2 = *(const shortx8*)&hin[(size_t)p2.x * H + f];
        shortx8 r3 = *(const shortx8*)&hin[(size_t)p3.x * H + f];
        float w0 = __builtin_bit_cast(float, p0.y);
        float w1 = __builtin_bit_cast(float, p1.y);
        float w2 = __builtin_bit_cast(float, p2.y);
        float w3 = __builtin_bit_cast(float, p3.y);
        #pragma unroll
        for (int j = 0; j < 8; ++j)
            acc[j] += w0 * b2f_s(r0[j]) + w1 * b2f_s(r1[j])
                    + w2 * b2f_s(r2[j]) + w3 * b2f_s(r3[j]);
    }
    for (; e < e1; e += 2) {
        int idx = e + half;
        bool valid = idx < e1;
        int2 pr = csr_sw[valid ? idx : e];
        float w = valid ? __builtin_bit_cast(float, pr.y) : 0.f;
        shortx8 r = *(const shortx8*)&hin[(size_t)pr.x * H + f];
        #pragma unroll
        for (int j = 0; j < 8; ++j) acc[j] += w * b2f_s(r[j]);
    }
    #pragma unroll
    for (int j = 0; j < 8; ++j) acc[j] += __shfl_xor(acc[j], 32, 64);
    if (half == 0) {
        float4 bi0 = *(const float4*)&bias[f];
        float4 bi1 = *(const float4*)&bias[f + 4];
        shortx8 o;
        o[0] = f2bs(acc[0] + bi0.x);
        o[1] = f2bs(acc[1] + bi0.y);
        o[2] = f2bs(acc[2] + bi0.z);
        o[3] = f2bs(acc[3] + bi0.w);
        o[4] = f2bs(acc[4] + bi1.x);
        o[5] = f2bs(acc[5] + bi1.y);
        o[6] = f2bs(acc[6] + bi1.z);
        o[7] = f2bs(acc[7] + bi1.w);
        *(shortx8*)&hout[(size_t)node * H + f] = o;
    }
}

// ---------- conv1 variant: adds wsum * cvec ----------
__global__ __launch_bounds__(256)
void k_agg_c(const unsigned short* __restrict__ hin, unsigned short* __restrict__ hout,
             const int* __restrict__ row_ptr, const int2* __restrict__ csr_sw,
             const float* __restrict__ dinv, const float* __restrict__ bias,
             const float* __restrict__ cvec, int N) {
    const int H = 256;
    int node = blockIdx.x * 4 + (threadIdx.x >> 6);
    if (node >= N) return;
    int lane = threadIdx.x & 63;
    int half = lane >> 5;
    int f = (lane & 31) * 8;
    float acc[8];
    float ws;
    float di = dinv[node];
    if (half == 0) {
        shortx8 hv = *(const shortx8*)&hin[(size_t)node * H + f];
        float sl = di * di;
        ws = sl;
        #pragma unroll
        for (int j = 0; j < 8; ++j) acc[j] = b2f_s(hv[j]) * sl;
    } else {
        ws = 0.f;
        #pragma unroll
        for (int j = 0; j < 8; ++j) acc[j] = 0.f;
    }
    int e0 = row_ptr[node], e1 = row_ptr[node + 1];
    int e = e0;
    for (; e + 8 <= e1; e += 8) {
        int2 p0 = csr_sw[e + 0 + half];
        int2 p1 = csr_sw[e + 2 + half];
        int2 p2 = csr_sw[e + 4 + half];
        int2 p3 = csr_sw[e + 6 + half];
        shortx8 r0 = *(const shortx8*)&hin[(size_t)p0.x * H + f];
        shortx8 r1 = *(const shortx8*)&hin[(size_t)p1.x * H + f];
        shortx8 r2 = *(const shortx8*)&hin[(size_t)p2.x * H + f];
        shortx8 r3 = *(const shortx8*)&hin[(size_t)p3.x * H + f];
        float w0 = __builtin_bit_cast(float, p0.y);
        float w1 = __builtin_bit_cast(float, p1.y);
        float w2 = __builtin_bit_cast(float, p2.y);
        float w3 = __builtin_bit_cast(float, p3.y);
        ws += (w0 + w1) + (w2 + w3);
        #pragma unroll
        for (int j = 0; j < 8; ++j)
            acc[j] += w0 * b2f_s(r0[j]) + w1 * b2f_s(r1[j])
                    + w2 * b2f_s(r2[j]) + w3 * b2f_s(r3[j]);
    }
    for (; e < e1; e += 2) {
        int idx = e + half;
        bool valid = idx < e1;
        int2 pr = csr_sw[valid ? idx : e];
        float w = valid ? __builtin_bit_cast(float, pr.y) : 0.f;
        shortx8 r = *(const shortx8*)&hin[(size_t)pr.x * H + f];
        ws += w;
        #pragma unroll
        for (int j = 0; j < 8; ++j) acc[j] += w * b2f_s(r[j]);
    }
    #pragma unroll
    for (int j = 0; j < 8; ++j) acc[j] += __shfl_xor(acc[j], 32, 64);
    ws += __shfl_xor(ws, 32, 64);
    if (half == 0) {
        float4 bi0 = *(const float4*)&bias[f];
        float4 bi1 = *(const float4*)&bias[f + 4];
        float4 c0 = *(const float4*)&cvec[f];
        float4 c1 = *(const float4*)&cvec[f + 4];
        bi0.x += ws * c0.x; bi0.y += ws * c0.y;
        bi0.z += ws * c0.z; bi0.w += ws * c0.w;
        bi1.x += ws * c1.x; bi1.y += ws * c1.y;
        bi1.z += ws * c1.z; bi1.w += ws * c1.w;
        shortx8 o;
        o[0] = f2bs(acc[0] + bi0.x);
        o[1] = f2bs(acc[1] + bi0.y);
        o[2] = f2bs(acc[2] + bi0.z);
        o[3] = f2bs(acc[3] + bi0.w);
        o[4] = f2bs(acc[4] + bi1.x);
        o[5] = f2bs(acc[5] + bi1.y);
        o[6] = f2bs(acc[6] + bi1.z);
        o[7] = f2bs(acc[7] + bi1.w);
        *(shortx8*)&hout[(size_t)node * H + f] = o;
    }
}

// ---------- head: h @ Wd' + bd' then sigmoid (BN2 pre-folded into Wd'), 4 nodes/block ----------
__global__ __launch_bounds__(256)
void k_head(const unsigned short* __restrict__ h, const float* __restrict__ Wdp,
            const float* __restrict__ bdp, float* __restrict__ out, int N) {
    int node = blockIdx.x * 4 + (threadIdx.x >> 6);
    if (node >= N) return;
    int lane = threadIdx.x & 63;
    int f = lane * 4;
    shortx4 hv = *(const shortx4*)&h[(size_t)node * 256 + f];
    float v0 = b2f_s(hv[0]);
    float v1 = b2f_s(hv[1]);
    float v2 = b2f_s(hv[2]);
    float v3 = b2f_s(hv[3]);
    float s[5];
    #pragma unroll
    for (int j = 0; j < 5; ++j) {
        s[j] = v0 * Wdp[(f + 0) * 5 + j] + v1 * Wdp[(f + 1) * 5 + j] +
               v2 * Wdp[(f + 2) * 5 + j] + v3 * Wdp[(f + 3) * 5 + j];
    }
    #pragma unroll
    for (int off = 32; off > 0; off >>= 1) {
        #pragma unroll
        for (int j = 0; j < 5; ++j) s[j] += __shfl_down(s[j], off, 64);
    }
    if (lane == 0) {
        #pragma unroll
        for (int j = 0; j < 5; ++j) {
            float z = s[j] + bdp[j];
            out[(size_t)node * 5 + j] = 1.f / (1.f + expf(-z));
        }
    }
}

extern "C" void kernel_launch(void* const* d_in, const int* in_sizes, int n_in,
                              void* d_out, int out_size, void* d_ws, size_t ws_size,
                              hipStream_t stream) {
    const float* x      = (const float*)d_in[0];
    const void*  ei_raw = d_in[1];
    const float* gamma1 = (const float*)d_in[2];
    const float* beta1  = (const float*)d_in[3];
    const float* W1 = (const float*)d_in[4];
    const float* b1 = (const float*)d_in[5];
    const float* W2 = (const float*)d_in[6];
    const float* b2 = (const float*)d_in[7];
    const float* W3 = (const float*)d_in[8];
    const float* b3 = (const float*)d_in[9];
    const float* W4 = (const float*)d_in[10];
    const float* b4 = (const float*)d_in[11];
    const float* gamma2 = (const float*)d_in[12];
    const float* beta2  = (const float*)d_in[13];
    const float* Wd = (const float*)d_in[14];
    const float* bd = (const float*)d_in[15];

    const int F = in_sizes[2];        // 512
    const int N = in_sizes[0] / F;    // 50000
    const int E = in_sizes[1] / 2;    // 800000
    const int H = in_sizes[5];        // 256
    const int Mpad = ((N + 127) / 128) * 128;   // 50048
    const int NB   = (N + 1023) / 1024;
    float* out = (float*)d_out;

    char* p = (char*)d_ws;
    auto alloc = [&](size_t bytes) {
        void* r = (void*)p;
        p += (bytes + 255) & ~(size_t)255;
        return r;
    };
    int*   flag    = (int*)  alloc(4);
    // ---- contiguous zero-init group ----
    char*  zstart  = p;
    int*   cnt     = (int*)  alloc((size_t)N * 4);
    float* colsum8 = (float*)alloc((size_t)8 * F * 4);
    float* colsq8  = (float*)alloc((size_t)8 * F * 4);
    float* colsum2 = (float*)alloc((size_t)4 * H * 4);
    float* colsq2  = (float*)alloc((size_t)4 * H * 4);
    float* cvec    = (float*)alloc((size_t)H * 4);
    size_t zbytes  = (size_t)(p - zstart);
    int*   row_ptr = (int*)  alloc(((size_t)N + 1) * 4);
    int*   seq     = (int*)  alloc((size_t)E * 4);
    float* dinv    = (float*)alloc((size_t)N * 4);
    int2*  csr_sw  = (int2*) alloc((size_t)E * 8);
    int*   bsum    = (int*)  alloc((size_t)NB * 4);
    float* bna     = (float*)alloc((size_t)F * 4);
    float* bnb     = (float*)alloc((size_t)F * 4);
    float* Wdp     = (float*)alloc((size_t)H * 5 * 4);
    float* bdp     = (float*)alloc(5 * 4);
    unsigned short* W1t = (unsigned short*)alloc((size_t)F * H * 2);
    unsigned short* W2t = (unsigned short*)alloc((size_t)H * H * 2);
    unsigned short* W3t = (unsigned short*)alloc((size_t)H * H * 2);
    unsigned short* W4t = (unsigned short*)alloc((size_t)H * H * 2);
    unsigned short* xb  = (unsigned short*)alloc((size_t)Mpad * F * 2);
    unsigned short* hbA = (unsigned short*)alloc((size_t)Mpad * H * 2);
    unsigned short* hbB = (unsigned short*)alloc((size_t)Mpad * H * 2);

    hipMemsetAsync(zstart, 0, zbytes, stream);
    hipMemsetAsync(xb + (size_t)N * F, 0, (size_t)(Mpad - N) * F * 2, stream);

    // graph build (single atomic pass: count+seq, then scan, then place)
    int n_check = (E >= 2048) ? 2048 : E;
    k_detect<<<1, 256, 0, stream>>>((const unsigned int*)ei_raw, n_check, flag);
    k_count_seq<<<(E + 255) / 256, 256, 0, stream>>>(ei_raw, flag, cnt, seq, E);
    k_scan_sum<<<NB, 1024, 0, stream>>>(cnt, bsum, N);
    k_scan_part<<<1, 1024, 0, stream>>>(bsum, NB);
    k_scan_final<<<NB, 1024, 0, stream>>>(cnt, bsum, row_ptr, dinv, N);
    k_place<<<(E + 255) / 256, 256, 0, stream>>>(ei_raw, flag, row_ptr, seq, dinv, csr_sw, E);

    // BN1 stats + raw cast (single pass over x)
    k_bnstats_cast<<<1024, 256, 0, stream>>>(x, xb, colsum8, colsq8, N, F);
    k_bnfin<<<(F + 255) / 256, 256, 0, stream>>>(colsum8, colsq8, gamma1, beta1, bna, bnb, N, F, 8);

    // weight prep (W1 scaled by bna) + cvec in one launch
    int tot = F * H + 3 * H * H;
    int wblocks = (tot + 255) / 256;
    k_prep_w<<<wblocks + 8, 256, 0, stream>>>(W1, W2, W3, W4, W1t, W2t, W3t, W4t,
                                              bna, bnb, cvec, F, H, wblocks);

    dim3 gg(Mpad / 128, H / 128);
    int aggb = (N + 3) / 4;
    // conv1 (BN1 folded: xb raw, W1t pre-scaled, cvec correction via wsum)
    k_gemm_bf16<<<gg, 256, 0, stream>>>(xb, W1t, hbA, F, H);
    k_agg_c<<<aggb, 256, 0, stream>>>(hbA, hbB, row_ptr, csr_sw, dinv, b1, cvec, N);
    // conv2
    k_gemm_bf16<<<gg, 256, 0, stream>>>(hbB, W2t, hbA, H, H);
    k_agg<<<aggb, 256, 0, stream>>>(hbA, hbB, row_ptr, csr_sw, dinv, b2, N);
    // conv3
    k_gemm_bf16<<<gg, 256, 0, stream>>>(hbB, W3t, hbA, H, H);
    k_agg<<<aggb, 256, 0, stream>>>(hbA, hbB, row_ptr, csr_sw, dinv, b3, N);
    // conv4
    k_gemm_bf16<<<gg, 256, 0, stream>>>(hbB, W4t, hbA, H, H);
    k_agg<<<aggb, 256, 0, stream>>>(hbA, hbB, row_ptr, csr_sw, dinv, b4, N);

    // BN2 + head (BN2 affine folded into head weights)
    k_bnstats_b<<<1024, 256, 0, stream>>>(hbB, colsum2, colsq2, N, H);
    k_bnfin<<<(H + 255) / 256, 256, 0, stream>>>(colsum2, colsq2, gamma2, beta2, bna, bnb, N, H, 4);
    k_prep_hd<<<1, 256, 0, stream>>>(Wd, bd, bna, bnb, Wdp, bdp, H);
    k_head<<<(N + 3) / 4, 256, 0, stream>>>(hbB, Wdp, bdp, out, N);
}